// Round 4
// baseline (645.003 us; speedup 1.0000x reference)
//
#include <hip/hip_runtime.h>

typedef unsigned short u16;
typedef unsigned int   u32;
typedef short bf16x8 __attribute__((ext_vector_type(8)));
typedef float f32x16 __attribute__((ext_vector_type(16)));

#define NB    8
#define NP    3136
#define DIM   256
#define PTILE 8
#define NEGM  (-100.0f)
#define QKSCALE 0.17677669529663687f

// LDS (64 KiB total), regions reused across barrier-separated phases:
//  @0      A_hi / Q(bf16,64B rows,XOR) / attnout_hi / z1_hi   (16K)
//  @16384  A_lo / K(bf16)              / attnout_lo / z1_lo   (16K)
//  @32768  V (f32, 128B rows, XOR)                            (32K)
#define LDS_ALO 16384
#define LDS_V   32768
#define LDS_SZ  65536

__device__ __forceinline__ u16 f2bf(float v) {
  u32 u = __float_as_uint(v);
  u = (u + 0x7FFFu + ((u >> 16) & 1u)) >> 16;
  return (u16)u;
}
__device__ __forceinline__ float bf2f(u16 h) {
  return __uint_as_float(((u32)h) << 16);
}
__device__ __forceinline__ float bflo(u32 w) { return __uint_as_float(w << 16); }
__device__ __forceinline__ float bfhi(u32 w) { return __uint_as_float(w & 0xffff0000u); }

// Q/K row swizzle: bits 4-5 only (64B rows -> always in-row, injective).
__device__ __forceinline__ int qksw(int row) {
  return ((row ^ (row >> 2)) & 3) << 4;
}

template<int MASKI>
__device__ __forceinline__ float maskv(int i, int j) {
  if (MASKI == 0) return ((i ^ j) == 3) ? NEGM : 0.f;
  return (i >= 2 || ((i ^ j) & 1)) ? NEGM : 0.f;
}

// ---------------- global-token means (deterministic 2-pass) ----------------
__global__ void mean_partial(const float* __restrict__ x,
                             const float* __restrict__ y,
                             float* __restrict__ part) {
  const int chunk = blockIdx.x;
  const int ab = blockIdx.y;
  const int b = ab & 7;
  const float* src = (ab >> 3) ? y : x;
  const int d = threadIdx.x;
  float s = 0.f;
  const int p0 = chunk * 98;  // 3136 = 32*98
  for (int i = 0; i < 98; i++)
    s += src[((size_t)b * NP + p0 + i) * DIM + d];
  part[((size_t)ab * 32 + chunk) * DIM + d] = s;
}

__global__ void mean_final(const float* __restrict__ part, float* __restrict__ g) {
  const int ab = blockIdx.x;
  const int d = threadIdx.x;
  float s = 0.f;
  for (int c = 0; c < 32; c++) s += part[((size_t)ab * 32 + c) * DIM + d];
  g[ab * DIM + d] = s * (1.0f / 3136.0f);
}

// ---------------- W -> packed hi/lo bf16 fragments ----------------
// Fragment order: [(ntile*16 + ks)*64 + lane]*8 ; lane holds B[n][k0..k0+7].
// is_qkv: pre-scale the Q output columns (n < 256) by QKSCALE.
__global__ void pack_w(const float* __restrict__ W, u16* __restrict__ hi,
                       u16* __restrict__ lo, int is_qkv) {
  const int nt = blockIdx.x, ks = blockIdx.y, lane = threadIdx.x;
  const int n  = nt * 32 + (lane & 31);
  const int k0 = ks * 16 + ((lane >> 5) << 3);
  const float scale = (is_qkv && n < 256) ? QKSCALE : 1.0f;
  const float* src = W + (size_t)n * 256 + k0;
  const size_t o = (((size_t)nt * 16 + ks) * 64 + lane) * 8;
#pragma unroll
  for (int j = 0; j < 8; j++) {
    float v = src[j] * scale;
    u16 h = f2bf(v);
    hi[o + j] = h;
    lo[o + j] = f2bf(v - bf2f(h));
  }
}

// ---------------- per-stage body (A-frags in LDS -> GEMM2 acc in regs) -----
template<int MASKI>
__device__ __forceinline__ f32x16 stage_body(
    char* lds, int tid, int lane, int wave,
    const u16* __restrict__ wq_hi, const u16* __restrict__ wq_lo,
    const u16* __restrict__ wo_hi, const u16* __restrict__ wo_lo) {

  const int arow = lane & 31;
  const int kgrp = (lane >> 5) << 3;

  // ---- GEMM1: QKV(32x768) = Z @ Wqkv^T, split-bf16 3-pass ----
  f32x16 acc[3];
#pragma unroll
  for (int t = 0; t < 3; t++)
#pragma unroll
    for (int i = 0; i < 16; i++) acc[t][i] = 0.f;

  const int nt0 = wave * 3;
  for (int ks = 0; ks < 16; ks++) {
    const int bo = (arow * 512 + (ks * 16 + kgrp) * 2) ^ ((arow & 15) << 4);
    bf16x8 ahi = *(const bf16x8*)(lds + bo);
    bf16x8 alo = *(const bf16x8*)(lds + LDS_ALO + bo);
#pragma unroll
    for (int t = 0; t < 3; t++) {
      const size_t o = (((size_t)(nt0 + t) * 16 + ks) * 64 + lane) * 8;
      bf16x8 bhi = *(const bf16x8*)(wq_hi + o);
      bf16x8 blo = *(const bf16x8*)(wq_lo + o);
      __builtin_amdgcn_s_setprio(1);
      acc[t] = __builtin_amdgcn_mfma_f32_32x32x16_bf16(ahi, bhi, acc[t], 0, 0, 0);
      acc[t] = __builtin_amdgcn_mfma_f32_32x32x16_bf16(ahi, blo, acc[t], 0, 0, 0);
      acc[t] = __builtin_amdgcn_mfma_f32_32x32x16_bf16(alo, bhi, acc[t], 0, 0, 0);
      __builtin_amdgcn_s_setprio(0);
    }
  }
  __syncthreads();  // A region dead; safe to overwrite with Q/K; V disjoint

  // ---- scatter acc -> Q(bf16,64B,XOR) / K / V(f32,128B,XOR) ----
  {
    const int cl = lane & 31;
    const int rh = (lane >> 5) << 2;
#pragma unroll
    for (int t = 0; t < 3; t++) {
      const int c    = (nt0 + t) * 32 + cl;
      const int head = (c >> 5) & 7;
      const int d    = c & 31;
      const int sel  = c >> 8;  // 0=Q 1=K 2=V
#pragma unroll
      for (int i = 0; i < 16; i++) {
        const int r      = (i & 3) + ((i >> 2) << 3) + rh;   // 0..31
        const int rowidx = ((r >> 2) * 8 + head) * 4 + (r & 3);
        const float v    = acc[t][i];
        if (sel == 0)
          *(u16*)(lds + rowidx * 64 + ((d * 2) ^ qksw(rowidx))) = f2bf(v);
        else if (sel == 1)
          *(u16*)(lds + LDS_ALO + rowidx * 64 + ((d * 2) ^ qksw(rowidx))) = f2bf(v);
        else
          *(float*)(lds + LDS_V + rowidx * 128 + ((d * 4) ^ ((rowidx & 7) << 4))) = v;
      }
    }
  }
  __syncthreads();

  // ---- attention dots: item=(pos,head,row), thread-pair split over d ----
  float p0, p1, p2, p3;
  const int item  = tid >> 1;          // 0..255
  const int half  = tid & 1;
  const int apos  = item >> 5;         // 0..7
  const int ahead = (item >> 2) & 7;
  const int arowt = item & 3;
  const int abase = (apos * 8 + ahead) * 4;
  const int d0b   = half * 32;         // byte offset of this half's 16 dims (bf16)
  {
    const int qr  = abase + arowt;
    const int qsw = qksw(qr);
    uint2 qw[4];
#pragma unroll
    for (int u = 0; u < 4; u++)
      qw[u] = *(const uint2*)(lds + qr * 64 + ((d0b + 8 * u) ^ qsw));
    float qf[16];
#pragma unroll
    for (int u = 0; u < 4; u++) {
      qf[4 * u + 0] = bflo(qw[u].x); qf[4 * u + 1] = bfhi(qw[u].x);
      qf[4 * u + 2] = bflo(qw[u].y); qf[4 * u + 3] = bfhi(qw[u].y);
    }
    float dots[4];
#pragma unroll
    for (int j = 0; j < 4; j++) {
      const int kr  = abase + j;
      const int ksw = qksw(kr);
      float s = 0.f;
#pragma unroll
      for (int u = 0; u < 4; u++) {
        uint2 kw = *(const uint2*)(lds + LDS_ALO + kr * 64 + ((d0b + 8 * u) ^ ksw));
        s += qf[4 * u + 0] * bflo(kw.x) + qf[4 * u + 1] * bfhi(kw.x)
           + qf[4 * u + 2] * bflo(kw.y) + qf[4 * u + 3] * bfhi(kw.y);
      }
      dots[j] = s;
    }
#pragma unroll
    for (int j = 0; j < 4; j++) {
      dots[j] += __shfl_xor(dots[j], 1);
      dots[j] += maskv<MASKI>(arowt, j);
    }
    const float mx = fmaxf(fmaxf(dots[0], dots[1]), fmaxf(dots[2], dots[3]));
    const float e0 = __expf(dots[0] - mx), e1 = __expf(dots[1] - mx);
    const float e2 = __expf(dots[2] - mx), e3 = __expf(dots[3] - mx);
    const float inv = 1.f / (e0 + e1 + e2 + e3);
    p0 = e0 * inv; p1 = e1 * inv; p2 = e2 * inv; p3 = e3 * inv;
  }
  __syncthreads();  // Q/K reads done; region now reusable for attnout frags

  // ---- PV (this thread's 16 dims) + write attnout hi/lo A-frags ----
  {
    const int dv0 = half * 64;  // byte offset of this half's 16 f32
    const int R   = apos * 4 + arowt;   // 0..31
    const int Rsw = (R & 15) << 4;
    const int s0 = (abase & 7) << 4;          // V row swizzles (abase..abase+3)
    const int s1 = ((abase + 1) & 7) << 4;
    const int s2 = ((abase + 2) & 7) << 4;
    const int s3 = ((abase + 3) & 7) << 4;
    const char* vb = lds + LDS_V;
#pragma unroll
    for (int u = 0; u < 4; u++) {
      const int db = dv0 + 16 * u;
      float4 a0 = *(const float4*)(vb + (abase + 0) * 128 + (db ^ s0));
      float4 a1 = *(const float4*)(vb + (abase + 1) * 128 + (db ^ s1));
      float4 a2 = *(const float4*)(vb + (abase + 2) * 128 + (db ^ s2));
      float4 a3 = *(const float4*)(vb + (abase + 3) * 128 + (db ^ s3));
      float o0 = p0 * a0.x + p1 * a1.x + p2 * a2.x + p3 * a3.x;
      float o1 = p0 * a0.y + p1 * a1.y + p2 * a2.y + p3 * a3.y;
      float o2 = p0 * a0.z + p1 * a1.z + p2 * a2.z + p3 * a3.z;
      float o3 = p0 * a0.w + p1 * a1.w + p2 * a2.w + p3 * a3.w;
      const int col = ahead * 32 + half * 16 + u * 4;  // even
      u16 h0 = f2bf(o0), h1 = f2bf(o1), h2 = f2bf(o2), h3 = f2bf(o3);
      u16 l0 = f2bf(o0 - bf2f(h0)), l1 = f2bf(o1 - bf2f(h1));
      u16 l2 = f2bf(o2 - bf2f(h2)), l3 = f2bf(o3 - bf2f(h3));
      const int boA = (R * 512 + col * 2) ^ Rsw;
      const int boB = (R * 512 + (col + 2) * 2) ^ Rsw;
      *(u32*)(lds + boA)           = (u32)h0 | ((u32)h1 << 16);
      *(u32*)(lds + boB)           = (u32)h2 | ((u32)h3 << 16);
      *(u32*)(lds + LDS_ALO + boA) = (u32)l0 | ((u32)l1 << 16);
      *(u32*)(lds + LDS_ALO + boB) = (u32)l2 | ((u32)l3 << 16);
    }
  }
  __syncthreads();

  // ---- GEMM2: out(32x256) = attnout @ Wout^T ----
  f32x16 acc2;
#pragma unroll
  for (int i = 0; i < 16; i++) acc2[i] = 0.f;

  for (int ks = 0; ks < 16; ks++) {
    const int bo = (arow * 512 + (ks * 16 + kgrp) * 2) ^ ((arow & 15) << 4);
    bf16x8 ahi = *(const bf16x8*)(lds + bo);
    bf16x8 alo = *(const bf16x8*)(lds + LDS_ALO + bo);
    const size_t o = (((size_t)wave * 16 + ks) * 64 + lane) * 8;
    bf16x8 bhi = *(const bf16x8*)(wo_hi + o);
    bf16x8 blo = *(const bf16x8*)(wo_lo + o);
    __builtin_amdgcn_s_setprio(1);
    acc2 = __builtin_amdgcn_mfma_f32_32x32x16_bf16(ahi, bhi, acc2, 0, 0, 0);
    acc2 = __builtin_amdgcn_mfma_f32_32x32x16_bf16(ahi, blo, acc2, 0, 0, 0);
    acc2 = __builtin_amdgcn_mfma_f32_32x32x16_bf16(alo, bhi, acc2, 0, 0, 0);
    __builtin_amdgcn_s_setprio(0);
  }
  return acc2;  // caller must __syncthreads before reusing @0..32K
}

// ---------------- fused double-stage kernel ----------------
__global__ __launch_bounds__(512, 4)
void fused_kernel(const float* __restrict__ x, const float* __restrict__ y,
                  const float* __restrict__ g, float* __restrict__ outp,
                  const u16* __restrict__ wq0_hi, const u16* __restrict__ wq0_lo,
                  const u16* __restrict__ wo0_hi, const u16* __restrict__ wo0_lo,
                  const float* __restrict__ bout0,
                  const u16* __restrict__ wq1_hi, const u16* __restrict__ wq1_lo,
                  const u16* __restrict__ wo1_hi, const u16* __restrict__ wo1_lo,
                  const float* __restrict__ bout1) {
  extern __shared__ char lds[];
  const int tid  = threadIdx.x;
  const int lane = tid & 63;
  const int wave = tid >> 6;
  const int b    = blockIdx.y;
  const int pos0 = blockIdx.x * PTILE;

  // ---- stage z tile (32 rows x 256) into A_hi/A_lo frags ----
  {
    const int r   = tid >> 4;          // 0..31
    const int cb  = (tid & 15) * 16;
    const int pos = pos0 + (r >> 2);
    const int tok = r & 3;
    const float* src;
    if (tok == 0)      src = x + ((size_t)b * NP + pos) * DIM;
    else if (tok == 1) src = y + ((size_t)b * NP + pos) * DIM;
    else if (tok == 2) src = g + b * DIM;
    else               src = g + (8 + b) * DIM;
    const int sw = (r & 15) << 4;
#pragma unroll
    for (int u = 0; u < 4; u++) {
      const int col = cb + u * 4;
      float4 v = *(const float4*)(src + col);
      u16 h0 = f2bf(v.x), h1 = f2bf(v.y), h2 = f2bf(v.z), h3 = f2bf(v.w);
      u16 l0 = f2bf(v.x - bf2f(h0)), l1 = f2bf(v.y - bf2f(h1));
      u16 l2 = f2bf(v.z - bf2f(h2)), l3 = f2bf(v.w - bf2f(h3));
      uint2 hw, lw;
      hw.x = (u32)h0 | ((u32)h1 << 16); hw.y = (u32)h2 | ((u32)h3 << 16);
      lw.x = (u32)l0 | ((u32)l1 << 16); lw.y = (u32)l2 | ((u32)l3 << 16);
      const int bo = (r * 512 + col * 2) ^ sw;
      *(uint2*)(lds + bo)           = hw;
      *(uint2*)(lds + LDS_ALO + bo) = lw;
    }
  }
  __syncthreads();

  // ---- stage 0 ----
  f32x16 a2 = stage_body<0>(lds, tid, lane, wave, wq0_hi, wq0_lo, wo0_hi, wo0_lo);
  __syncthreads();  // all attnout-frag reads complete

  // ---- z1 = out0 + bias0 -> A-frags for stage 1 ----
  const int c  = wave * 32 + (lane & 31);
  const int rh = (lane >> 5) << 2;
  {
    const float bc = bout0[c];
#pragma unroll
    for (int i = 0; i < 16; i++) {
      const int r  = (i & 3) + ((i >> 2) << 3) + rh;
      const float v = a2[i] + bc;
      u16 h = f2bf(v);
      u16 l = f2bf(v - bf2f(h));
      const int bo = (r * 512 + c * 2) ^ ((r & 15) << 4);
      *(u16*)(lds + bo)           = h;
      *(u16*)(lds + LDS_ALO + bo) = l;
    }
  }
  __syncthreads();

  // ---- stage 1 ----
  f32x16 b2 = stage_body<1>(lds, tid, lane, wave, wq1_hi, wq1_lo, wo1_hi, wo1_lo);

  // ---- final epilogue: tok0 -> x1, tok1 -> y1 ----
  {
    const float bc = bout1[c];
    const size_t TOT = (size_t)NB * NP * DIM;
#pragma unroll
    for (int i = 0; i < 16; i++) {
      const int r   = (i & 3) + ((i >> 2) << 3) + rh;
      const int pos = pos0 + (r >> 2);
      const int tok = r & 3;
      const float v = b2[i] + bc;
      if (tok == 0)      outp[((size_t)b * NP + pos) * DIM + c] = v;
      else if (tok == 1) outp[TOT + ((size_t)b * NP + pos) * DIM + c] = v;
    }
  }
}

extern "C" void kernel_launch(void* const* d_in, const int* in_sizes, int n_in,
                              void* d_out, int out_size, void* d_ws, size_t ws_size,
                              hipStream_t stream) {
  const float* x     = (const float*)d_in[0];
  const float* y     = (const float*)d_in[1];
  const float* wqkv0 = (const float*)d_in[2];
  const float* wout0 = (const float*)d_in[3];
  const float* bout0 = (const float*)d_in[4];
  const float* wqkv1 = (const float*)d_in[5];
  const float* wout1 = (const float*)d_in[6];
  const float* bout1 = (const float*)d_in[7];

  float* part = (float*)d_ws;                        // 16*32*256 f32
  float* g    = part + (size_t)16 * 32 * DIM;        // 16*256 f32
  u16* w = (u16*)(g + 16 * DIM);
  u16* wq0_hi = w; w += 768 * 256;
  u16* wq0_lo = w; w += 768 * 256;
  u16* wo0_hi = w; w += 256 * 256;
  u16* wo0_lo = w; w += 256 * 256;
  u16* wq1_hi = w; w += 768 * 256;
  u16* wq1_lo = w; w += 768 * 256;
  u16* wo1_hi = w; w += 256 * 256;
  u16* wo1_lo = w; w += 256 * 256;

  mean_partial<<<dim3(32, 16), dim3(256), 0, stream>>>(x, y, part);
  mean_final<<<dim3(16), dim3(256), 0, stream>>>(part, g);

  pack_w<<<dim3(24, 16), dim3(64), 0, stream>>>(wqkv0, wq0_hi, wq0_lo, 1);
  pack_w<<<dim3(8, 16),  dim3(64), 0, stream>>>(wout0, wo0_hi, wo0_lo, 0);
  pack_w<<<dim3(24, 16), dim3(64), 0, stream>>>(wqkv1, wq1_hi, wq1_lo, 1);
  pack_w<<<dim3(8, 16),  dim3(64), 0, stream>>>(wout1, wo1_hi, wo1_lo, 0);

  fused_kernel<<<dim3(NP / PTILE, NB), dim3(512), LDS_SZ, stream>>>(
      x, y, g, (float*)d_out,
      wq0_hi, wq0_lo, wo0_hi, wo0_lo, bout0,
      wq1_hi, wq1_lo, wo1_hi, wo1_lo, bout1);
}

// Round 5
// 608.988 us; speedup vs baseline: 1.0591x; 1.0591x over previous
//
#include <hip/hip_runtime.h>

typedef unsigned short u16;
typedef unsigned int   u32;
typedef short bf16x8 __attribute__((ext_vector_type(8)));
typedef float f32x16 __attribute__((ext_vector_type(16)));

#define NB    8
#define NP    3136
#define DIM   256
#define PTILE 8
#define NEGM  (-100.0f)
#define QKSCALE 0.17677669529663687f

// LDS (64 KiB), regions reused across barrier-separated phases:
//  @0      A_hi (16K)  -> V f32 (0..32K, 128B rows, XOR)  -> z1_hi (16K)
//  @16384  A_lo (16K)  -> (V cont.)                       -> z1_lo (16K)
//  @32768  Q bf16 (64B rows, XOR) -> attnout_hi frags (16K)
//  @49152  K bf16 (64B rows, XOR) -> attnout_lo frags (16K)
#define LDS_ALO 16384
#define LDS_Q   32768
#define LDS_K   49152
#define LDS_SZ  65536

__device__ __forceinline__ u16 f2bf(float v) {
  u32 u = __float_as_uint(v);
  u = (u + 0x7FFFu + ((u >> 16) & 1u)) >> 16;
  return (u16)u;
}
__device__ __forceinline__ float bf2f(u16 h) {
  return __uint_as_float(((u32)h) << 16);
}
__device__ __forceinline__ float bflo(u32 w) { return __uint_as_float(w << 16); }
__device__ __forceinline__ float bfhi(u32 w) { return __uint_as_float(w & 0xffff0000u); }

// Q/K row swizzle: bits 4-5 only (64B rows -> in-row, injective).
__device__ __forceinline__ int qksw(int row) {
  return ((row ^ (row >> 2)) & 3) << 4;
}

template<int MASKI>
__device__ __forceinline__ float maskv(int i, int j) {
  if (MASKI == 0) return ((i ^ j) == 3) ? NEGM : 0.f;
  return (i >= 2 || ((i ^ j) & 1)) ? NEGM : 0.f;
}

// ---------------- global-token means (deterministic 2-pass) ----------------
__global__ void mean_partial(const float* __restrict__ x,
                             const float* __restrict__ y,
                             float* __restrict__ part) {
  const int chunk = blockIdx.x;
  const int ab = blockIdx.y;
  const int b = ab & 7;
  const float* src = (ab >> 3) ? y : x;
  const int d = threadIdx.x;
  float s = 0.f;
  const int p0 = chunk * 98;  // 3136 = 32*98
  for (int i = 0; i < 98; i++)
    s += src[((size_t)b * NP + p0 + i) * DIM + d];
  part[((size_t)ab * 32 + chunk) * DIM + d] = s;
}

__global__ void mean_final(const float* __restrict__ part, float* __restrict__ g) {
  const int ab = blockIdx.x;
  const int d = threadIdx.x;
  float s = 0.f;
  for (int c = 0; c < 32; c++) s += part[((size_t)ab * 32 + c) * DIM + d];
  g[ab * DIM + d] = s * (1.0f / 3136.0f);
}

// ---------------- W -> packed hi/lo bf16 fragments ----------------
// Fragment order: [(ntile*16 + ks)*64 + lane]*8 ; lane holds B[n][k0..k0+7].
// is_qkv: pre-scale the Q output columns (n < 256) by QKSCALE.
__global__ void pack_w(const float* __restrict__ W, u16* __restrict__ hi,
                       u16* __restrict__ lo, int is_qkv) {
  const int nt = blockIdx.x, ks = blockIdx.y, lane = threadIdx.x;
  const int n  = nt * 32 + (lane & 31);
  const int k0 = ks * 16 + ((lane >> 5) << 3);
  const float scale = (is_qkv && n < 256) ? QKSCALE : 1.0f;
  const float* src = W + (size_t)n * 256 + k0;
  const size_t o = (((size_t)nt * 16 + ks) * 64 + lane) * 8;
#pragma unroll
  for (int j = 0; j < 8; j++) {
    float v = src[j] * scale;
    u16 h = f2bf(v);
    hi[o + j] = h;
    lo[o + j] = f2bf(v - bf2f(h));
  }
}

// ---------------- per-stage body ----------------
// Entry: A-frags (hi@0, lo@16K) staged, barrier passed.
// Exit: returns GEMM2 acc (out tile cols wave*32..wave*32+31); all LDS dead.
template<int MASKI>
__device__ __forceinline__ f32x16 stage_body(
    char* lds, int tid, int lane, int wave,
    const u16* __restrict__ wq_hi, const u16* __restrict__ wq_lo,
    const u16* __restrict__ wo_hi, const u16* __restrict__ wo_lo) {

  const int arow = lane & 31;
  const int kgrp = (lane >> 5) << 3;
  const int cl   = lane & 31;
  const int rh   = (lane >> 5) << 2;

  // ---- GEMM1: wave w computes tiles {w}=Q, {8+w}=K, {16+w}=V (head=w) ----
  // One acc live per t; Q/K scatter immediately (upper 32K, no A conflict);
  // V acc held across the barrier.
  f32x16 accV;
#pragma unroll 1
  for (int t = 0; t < 3; t++) {
    f32x16 acc;
#pragma unroll
    for (int i = 0; i < 16; i++) acc[i] = 0.f;
    const int nt = t * 8 + wave;
    for (int ks = 0; ks < 16; ks++) {
      const int bo = (arow * 512 + (ks * 16 + kgrp) * 2) ^ ((arow & 15) << 4);
      bf16x8 ahi = *(const bf16x8*)(lds + bo);
      bf16x8 alo = *(const bf16x8*)(lds + LDS_ALO + bo);
      const size_t o = (((size_t)nt * 16 + ks) * 64 + lane) * 8;
      bf16x8 bhi = *(const bf16x8*)(wq_hi + o);
      bf16x8 blo = *(const bf16x8*)(wq_lo + o);
      __builtin_amdgcn_s_setprio(1);
      acc = __builtin_amdgcn_mfma_f32_32x32x16_bf16(ahi, bhi, acc, 0, 0, 0);
      acc = __builtin_amdgcn_mfma_f32_32x32x16_bf16(ahi, blo, acc, 0, 0, 0);
      acc = __builtin_amdgcn_mfma_f32_32x32x16_bf16(alo, bhi, acc, 0, 0, 0);
      __builtin_amdgcn_s_setprio(0);
    }
    if (t == 2) {
      accV = acc;
    } else {
      const int base = (t == 0) ? LDS_Q : LDS_K;
#pragma unroll
      for (int i = 0; i < 16; i++) {
        const int r      = (i & 3) + ((i >> 2) << 3) + rh;      // 0..31
        const int rowidx = ((r >> 2) * 8 + wave) * 4 + (r & 3); // 0..255
        *(u16*)(lds + base + rowidx * 64 + ((cl * 2) ^ qksw(rowidx))) = f2bf(acc[i]);
      }
    }
  }
  __syncthreads();  // all waves done reading A region (@0..32K)

  // ---- scatter V (f32, 128B rows, XOR) into @0..32K ----
#pragma unroll
  for (int i = 0; i < 16; i++) {
    const int r      = (i & 3) + ((i >> 2) << 3) + rh;
    const int rowidx = ((r >> 2) * 8 + wave) * 4 + (r & 3);
    *(float*)(lds + rowidx * 128 + ((cl * 4) ^ ((rowidx & 7) << 4))) = accV[i];
  }
  __syncthreads();

  // ---- attention dots: item=(pos,head,row), thread-pair split over d ----
  float p0, p1, p2, p3;
  const int item  = tid >> 1;          // 0..255
  const int half  = tid & 1;
  const int apos  = item >> 5;         // 0..7
  const int ahead = (item >> 2) & 7;
  const int arowt = item & 3;
  const int abase = (apos * 8 + ahead) * 4;
  const int d0b   = half * 32;         // byte offset of this half's 16 dims (bf16)
  {
    const int qr  = abase + arowt;
    const int qsw = qksw(qr);
    uint2 qw[4];
#pragma unroll
    for (int u = 0; u < 4; u++)
      qw[u] = *(const uint2*)(lds + LDS_Q + qr * 64 + ((d0b + 8 * u) ^ qsw));
    float qf[16];
#pragma unroll
    for (int u = 0; u < 4; u++) {
      qf[4 * u + 0] = bflo(qw[u].x); qf[4 * u + 1] = bfhi(qw[u].x);
      qf[4 * u + 2] = bflo(qw[u].y); qf[4 * u + 3] = bfhi(qw[u].y);
    }
    float dots[4];
#pragma unroll
    for (int j = 0; j < 4; j++) {
      const int kr  = abase + j;
      const int ksw = qksw(kr);
      float s = 0.f;
#pragma unroll
      for (int u = 0; u < 4; u++) {
        uint2 kw = *(const uint2*)(lds + LDS_K + kr * 64 + ((d0b + 8 * u) ^ ksw));
        s += qf[4 * u + 0] * bflo(kw.x) + qf[4 * u + 1] * bfhi(kw.x)
           + qf[4 * u + 2] * bflo(kw.y) + qf[4 * u + 3] * bfhi(kw.y);
      }
      dots[j] = s;
    }
#pragma unroll
    for (int j = 0; j < 4; j++) {
      dots[j] += __shfl_xor(dots[j], 1);
      dots[j] += maskv<MASKI>(arowt, j);
    }
    const float mx = fmaxf(fmaxf(dots[0], dots[1]), fmaxf(dots[2], dots[3]));
    const float e0 = __expf(dots[0] - mx), e1 = __expf(dots[1] - mx);
    const float e2 = __expf(dots[2] - mx), e3 = __expf(dots[3] - mx);
    const float inv = 1.f / (e0 + e1 + e2 + e3);
    p0 = e0 * inv; p1 = e1 * inv; p2 = e2 * inv; p3 = e3 * inv;
  }
  __syncthreads();  // Q/K reads done; @32K..64K reusable for attnout frags

  // ---- PV (this thread's 16 dims) + write attnout hi/lo A-frags @32K/48K ----
  {
    const int dv0 = half * 64;  // byte offset of this half's 16 f32
    const int R   = apos * 4 + arowt;   // 0..31
    const int Rsw = (R & 15) << 4;
    const int s0 = (abase & 7) << 4;    // V row swizzles (abase..abase+3)
    const int s1 = ((abase + 1) & 7) << 4;
    const int s2 = ((abase + 2) & 7) << 4;
    const int s3 = ((abase + 3) & 7) << 4;
#pragma unroll
    for (int u = 0; u < 4; u++) {
      const int db = dv0 + 16 * u;
      float4 a0 = *(const float4*)(lds + (abase + 0) * 128 + (db ^ s0));
      float4 a1 = *(const float4*)(lds + (abase + 1) * 128 + (db ^ s1));
      float4 a2 = *(const float4*)(lds + (abase + 2) * 128 + (db ^ s2));
      float4 a3 = *(const float4*)(lds + (abase + 3) * 128 + (db ^ s3));
      float o0 = p0 * a0.x + p1 * a1.x + p2 * a2.x + p3 * a3.x;
      float o1 = p0 * a0.y + p1 * a1.y + p2 * a2.y + p3 * a3.y;
      float o2 = p0 * a0.z + p1 * a1.z + p2 * a2.z + p3 * a3.z;
      float o3 = p0 * a0.w + p1 * a1.w + p2 * a2.w + p3 * a3.w;
      const int col = ahead * 32 + half * 16 + u * 4;  // even
      u16 h0 = f2bf(o0), h1 = f2bf(o1), h2 = f2bf(o2), h3 = f2bf(o3);
      u16 l0 = f2bf(o0 - bf2f(h0)), l1 = f2bf(o1 - bf2f(h1));
      u16 l2 = f2bf(o2 - bf2f(h2)), l3 = f2bf(o3 - bf2f(h3));
      const int boA = (R * 512 + col * 2) ^ Rsw;
      const int boB = (R * 512 + (col + 2) * 2) ^ Rsw;
      *(u32*)(lds + LDS_Q + boA) = (u32)h0 | ((u32)h1 << 16);
      *(u32*)(lds + LDS_Q + boB) = (u32)h2 | ((u32)h3 << 16);
      *(u32*)(lds + LDS_K + boA) = (u32)l0 | ((u32)l1 << 16);
      *(u32*)(lds + LDS_K + boB) = (u32)l2 | ((u32)l3 << 16);
    }
  }
  __syncthreads();

  // ---- GEMM2: out(32x256) = attnout @ Wout^T (A-frags @32K/48K) ----
  f32x16 acc2;
#pragma unroll
  for (int i = 0; i < 16; i++) acc2[i] = 0.f;

  for (int ks = 0; ks < 16; ks++) {
    const int bo = (arow * 512 + (ks * 16 + kgrp) * 2) ^ ((arow & 15) << 4);
    bf16x8 ahi = *(const bf16x8*)(lds + LDS_Q + bo);
    bf16x8 alo = *(const bf16x8*)(lds + LDS_K + bo);
    const size_t o = (((size_t)wave * 16 + ks) * 64 + lane) * 8;
    bf16x8 bhi = *(const bf16x8*)(wo_hi + o);
    bf16x8 blo = *(const bf16x8*)(wo_lo + o);
    __builtin_amdgcn_s_setprio(1);
    acc2 = __builtin_amdgcn_mfma_f32_32x32x16_bf16(ahi, bhi, acc2, 0, 0, 0);
    acc2 = __builtin_amdgcn_mfma_f32_32x32x16_bf16(ahi, blo, acc2, 0, 0, 0);
    acc2 = __builtin_amdgcn_mfma_f32_32x32x16_bf16(alo, bhi, acc2, 0, 0, 0);
    __builtin_amdgcn_s_setprio(0);
  }
  return acc2;
  // Post-GEMM2, @0..32K is dead for ALL waves once this wave returns
  // (V reads ended at the pre-GEMM2 barrier), so the caller may write
  // z1 frags @0/16K without an extra barrier.
}

// ---------------- fused double-stage kernel ----------------
__global__ __launch_bounds__(512, 4)
void fused_kernel(const float* __restrict__ x, const float* __restrict__ y,
                  const float* __restrict__ g, float* __restrict__ outp,
                  const u16* __restrict__ wq0_hi, const u16* __restrict__ wq0_lo,
                  const u16* __restrict__ wo0_hi, const u16* __restrict__ wo0_lo,
                  const float* __restrict__ bout0,
                  const u16* __restrict__ wq1_hi, const u16* __restrict__ wq1_lo,
                  const u16* __restrict__ wo1_hi, const u16* __restrict__ wo1_lo,
                  const float* __restrict__ bout1) {
  extern __shared__ char lds[];
  const int tid  = threadIdx.x;
  const int lane = tid & 63;
  const int wave = tid >> 6;
  const int b    = blockIdx.y;
  const int pos0 = blockIdx.x * PTILE;

  // ---- stage z tile (32 rows x 256) into A_hi/A_lo frags @0/16K ----
  {
    const int r   = tid >> 4;          // 0..31
    const int cb  = (tid & 15) * 16;
    const int pos = pos0 + (r >> 2);
    const int tok = r & 3;
    const float* src;
    if (tok == 0)      src = x + ((size_t)b * NP + pos) * DIM;
    else if (tok == 1) src = y + ((size_t)b * NP + pos) * DIM;
    else if (tok == 2) src = g + b * DIM;
    else               src = g + (8 + b) * DIM;
    const int sw = (r & 15) << 4;
#pragma unroll
    for (int u = 0; u < 4; u++) {
      const int col = cb + u * 4;
      float4 v = *(const float4*)(src + col);
      u16 h0 = f2bf(v.x), h1 = f2bf(v.y), h2 = f2bf(v.z), h3 = f2bf(v.w);
      u16 l0 = f2bf(v.x - bf2f(h0)), l1 = f2bf(v.y - bf2f(h1));
      u16 l2 = f2bf(v.z - bf2f(h2)), l3 = f2bf(v.w - bf2f(h3));
      uint2 hw, lw;
      hw.x = (u32)h0 | ((u32)h1 << 16); hw.y = (u32)h2 | ((u32)h3 << 16);
      lw.x = (u32)l0 | ((u32)l1 << 16); lw.y = (u32)l2 | ((u32)l3 << 16);
      const int bo = (r * 512 + col * 2) ^ sw;
      *(uint2*)(lds + bo)           = hw;
      *(uint2*)(lds + LDS_ALO + bo) = lw;
    }
  }
  __syncthreads();

  // ---- stage 0 ----
  f32x16 a2 = stage_body<0>(lds, tid, lane, wave, wq0_hi, wq0_lo, wo0_hi, wo0_lo);

  // ---- z1 = out0 + bias0 -> A-frags @0/16K for stage 1 ----
  const int c  = wave * 32 + (lane & 31);
  const int rh = (lane >> 5) << 2;
  {
    const float bc = bout0[c];
#pragma unroll
    for (int i = 0; i < 16; i++) {
      const int r  = (i & 3) + ((i >> 2) << 3) + rh;
      const float v = a2[i] + bc;
      u16 h = f2bf(v);
      u16 l = f2bf(v - bf2f(h));
      const int bo = (r * 512 + c * 2) ^ ((r & 15) << 4);
      *(u16*)(lds + bo)           = h;
      *(u16*)(lds + LDS_ALO + bo) = l;
    }
  }
  __syncthreads();

  // ---- stage 1 ----
  f32x16 b2 = stage_body<1>(lds, tid, lane, wave, wq1_hi, wq1_lo, wo1_hi, wo1_lo);

  // ---- final epilogue: tok0 -> x1, tok1 -> y1 ----
  {
    const float bc = bout1[c];
    const size_t TOT = (size_t)NB * NP * DIM;
#pragma unroll
    for (int i = 0; i < 16; i++) {
      const int r   = (i & 3) + ((i >> 2) << 3) + rh;
      const int pos = pos0 + (r >> 2);
      const int tok = r & 3;
      const float v = b2[i] + bc;
      if (tok == 0)      outp[((size_t)b * NP + pos) * DIM + c] = v;
      else if (tok == 1) outp[TOT + ((size_t)b * NP + pos) * DIM + c] = v;
    }
  }
}

extern "C" void kernel_launch(void* const* d_in, const int* in_sizes, int n_in,
                              void* d_out, int out_size, void* d_ws, size_t ws_size,
                              hipStream_t stream) {
  const float* x     = (const float*)d_in[0];
  const float* y     = (const float*)d_in[1];
  const float* wqkv0 = (const float*)d_in[2];
  const float* wout0 = (const float*)d_in[3];
  const float* bout0 = (const float*)d_in[4];
  const float* wqkv1 = (const float*)d_in[5];
  const float* wout1 = (const float*)d_in[6];
  const float* bout1 = (const float*)d_in[7];

  float* part = (float*)d_ws;                        // 16*32*256 f32
  float* g    = part + (size_t)16 * 32 * DIM;        // 16*256 f32
  u16* w = (u16*)(g + 16 * DIM);
  u16* wq0_hi = w; w += 768 * 256;
  u16* wq0_lo = w; w += 768 * 256;
  u16* wo0_hi = w; w += 256 * 256;
  u16* wo0_lo = w; w += 256 * 256;
  u16* wq1_hi = w; w += 768 * 256;
  u16* wq1_lo = w; w += 768 * 256;
  u16* wo1_hi = w; w += 256 * 256;
  u16* wo1_lo = w; w += 256 * 256;

  mean_partial<<<dim3(32, 16), dim3(256), 0, stream>>>(x, y, part);
  mean_final<<<dim3(16), dim3(256), 0, stream>>>(part, g);

  pack_w<<<dim3(24, 16), dim3(64), 0, stream>>>(wqkv0, wq0_hi, wq0_lo, 1);
  pack_w<<<dim3(8, 16),  dim3(64), 0, stream>>>(wout0, wo0_hi, wo0_lo, 0);
  pack_w<<<dim3(24, 16), dim3(64), 0, stream>>>(wqkv1, wq1_hi, wq1_lo, 1);
  pack_w<<<dim3(8, 16),  dim3(64), 0, stream>>>(wout1, wo1_hi, wo1_lo, 0);

  fused_kernel<<<dim3(NP / PTILE, NB), dim3(512), LDS_SZ, stream>>>(
      x, y, g, (float*)d_out,
      wq0_hi, wq0_lo, wo0_hi, wo0_lo, bout0,
      wq1_hi, wq1_lo, wo1_hi, wo1_lo, bout1);
}

// Round 6
// 451.771 us; speedup vs baseline: 1.4277x; 1.3480x over previous
//
#include <hip/hip_runtime.h>

typedef unsigned short u16;
typedef unsigned int   u32;
typedef short bf16x8 __attribute__((ext_vector_type(8)));
typedef float f32x16 __attribute__((ext_vector_type(16)));

#define NB    8
#define NP    3136
#define DIM   256
#define PTILE 8
#define NEGM  (-100.0f)
#define QKSCALE 0.17677669529663687f

// LDS (64 KiB), regions reused across barrier-separated phases:
//  @0      A_hi (16K)  -> V f32 (0..32K, 128B rows, XOR)  -> z1_hi (16K)
//  @16384  A_lo (16K)  -> (V cont.)                       -> z1_lo (16K)
//  @32768  Q bf16 (64B rows, XOR) -> attnout_hi frags (16K)
//  @49152  K bf16 (64B rows, XOR) -> attnout_lo frags (16K)
#define LDS_ALO 16384
#define LDS_Q   32768
#define LDS_K   49152
#define LDS_SZ  65536

__device__ __forceinline__ u16 f2bf(float v) {
  u32 u = __float_as_uint(v);
  u = (u + 0x7FFFu + ((u >> 16) & 1u)) >> 16;
  return (u16)u;
}
__device__ __forceinline__ float bf2f(u16 h) {
  return __uint_as_float(((u32)h) << 16);
}
__device__ __forceinline__ float bflo(u32 w) { return __uint_as_float(w << 16); }
__device__ __forceinline__ float bfhi(u32 w) { return __uint_as_float(w & 0xffff0000u); }

__device__ __forceinline__ void phase_fence() {
  __builtin_amdgcn_sched_barrier(0);  // pin phases: no cross-phase code motion
}

// Q/K row swizzle: bits 4-5 only (64B rows -> in-row, injective).
__device__ __forceinline__ int qksw(int row) {
  return ((row ^ (row >> 2)) & 3) << 4;
}

template<int MASKI>
__device__ __forceinline__ float maskv(int i, int j) {
  if (MASKI == 0) return ((i ^ j) == 3) ? NEGM : 0.f;
  return (i >= 2 || ((i ^ j) & 1)) ? NEGM : 0.f;
}

// ---------------- global-token means (deterministic 2-pass) ----------------
__global__ void mean_partial(const float* __restrict__ x,
                             const float* __restrict__ y,
                             float* __restrict__ part) {
  const int chunk = blockIdx.x;
  const int ab = blockIdx.y;
  const int b = ab & 7;
  const float* src = (ab >> 3) ? y : x;
  const int d = threadIdx.x;
  float s = 0.f;
  const int p0 = chunk * 98;  // 3136 = 32*98
  for (int i = 0; i < 98; i++)
    s += src[((size_t)b * NP + p0 + i) * DIM + d];
  part[((size_t)ab * 32 + chunk) * DIM + d] = s;
}

__global__ void mean_final(const float* __restrict__ part, float* __restrict__ g) {
  const int ab = blockIdx.x;
  const int d = threadIdx.x;
  float s = 0.f;
  for (int c = 0; c < 32; c++) s += part[((size_t)ab * 32 + c) * DIM + d];
  g[ab * DIM + d] = s * (1.0f / 3136.0f);
}

// ---------------- W -> packed hi/lo bf16 fragments ----------------
// Fragment order: [(ntile*16 + ks)*64 + lane]*8 ; lane holds B[n][k0..k0+7].
// is_qkv: pre-scale the Q output columns (n < 256) by QKSCALE.
__global__ void pack_w(const float* __restrict__ W, u16* __restrict__ hi,
                       u16* __restrict__ lo, int is_qkv) {
  const int nt = blockIdx.x, ks = blockIdx.y, lane = threadIdx.x;
  const int n  = nt * 32 + (lane & 31);
  const int k0 = ks * 16 + ((lane >> 5) << 3);
  const float scale = (is_qkv && n < 256) ? QKSCALE : 1.0f;
  const float* src = W + (size_t)n * 256 + k0;
  const size_t o = (((size_t)nt * 16 + ks) * 64 + lane) * 8;
#pragma unroll
  for (int j = 0; j < 8; j++) {
    float v = src[j] * scale;
    u16 h = f2bf(v);
    hi[o + j] = h;
    lo[o + j] = f2bf(v - bf2f(h));
  }
}

// ---------------- per-stage body ----------------
// Entry: A-frags (hi@0, lo@16K) staged, barrier passed.
// Exit: returns GEMM2 acc (out tile cols wave*32..wave*32+31); all LDS dead.
template<int MASKI>
__device__ __forceinline__ f32x16 stage_body(
    char* lds, int tid, int lane, int wave,
    const u16* __restrict__ wq_hi, const u16* __restrict__ wq_lo,
    const u16* __restrict__ wo_hi, const u16* __restrict__ wo_lo) {

  const int arow = lane & 31;
  const int kgrp = (lane >> 5) << 3;
  const int cl   = lane & 31;
  const int rh   = (lane >> 5) << 2;

  // ---- GEMM1: wave w computes tiles {w}=Q, {8+w}=K, {16+w}=V (head=w) ----
  // One acc live per t; Q/K scatter immediately (upper 32K, no A conflict);
  // V acc held across the barrier. ks-loop unroll capped to bound the
  // in-flight-load register window (R5 spill root cause).
  f32x16 accV;
#pragma unroll 1
  for (int t = 0; t < 3; t++) {
    f32x16 acc;
#pragma unroll
    for (int i = 0; i < 16; i++) acc[i] = 0.f;
    const int nt = t * 8 + wave;
#pragma unroll 4
    for (int ks = 0; ks < 16; ks++) {
      const int bo = (arow * 512 + (ks * 16 + kgrp) * 2) ^ ((arow & 15) << 4);
      bf16x8 ahi = *(const bf16x8*)(lds + bo);
      bf16x8 alo = *(const bf16x8*)(lds + LDS_ALO + bo);
      const size_t o = (((size_t)nt * 16 + ks) * 64 + lane) * 8;
      bf16x8 bhi = *(const bf16x8*)(wq_hi + o);
      bf16x8 blo = *(const bf16x8*)(wq_lo + o);
      __builtin_amdgcn_s_setprio(1);
      acc = __builtin_amdgcn_mfma_f32_32x32x16_bf16(ahi, bhi, acc, 0, 0, 0);
      acc = __builtin_amdgcn_mfma_f32_32x32x16_bf16(ahi, blo, acc, 0, 0, 0);
      acc = __builtin_amdgcn_mfma_f32_32x32x16_bf16(alo, bhi, acc, 0, 0, 0);
      __builtin_amdgcn_s_setprio(0);
    }
    if (t == 2) {
      accV = acc;
    } else {
      const int base = (t == 0) ? LDS_Q : LDS_K;
#pragma unroll
      for (int i = 0; i < 16; i++) {
        const int r      = (i & 3) + ((i >> 2) << 3) + rh;      // 0..31
        const int rowidx = ((r >> 2) * 8 + wave) * 4 + (r & 3); // 0..255
        *(u16*)(lds + base + rowidx * 64 + ((cl * 2) ^ qksw(rowidx))) = f2bf(acc[i]);
      }
    }
  }
  __syncthreads();  // all waves done reading A region (@0..32K)
  phase_fence();

  // ---- scatter V (f32, 128B rows, XOR) into @0..32K ----
#pragma unroll
  for (int i = 0; i < 16; i++) {
    const int r      = (i & 3) + ((i >> 2) << 3) + rh;
    const int rowidx = ((r >> 2) * 8 + wave) * 4 + (r & 3);
    *(float*)(lds + rowidx * 128 + ((cl * 4) ^ ((rowidx & 7) << 4))) = accV[i];
  }
  __syncthreads();
  phase_fence();

  // ---- attention dots: item=(pos,head,row), thread-pair split over d ----
  float p0, p1, p2, p3;
  const int item  = tid >> 1;          // 0..255
  const int half  = tid & 1;
  const int apos  = item >> 5;         // 0..7
  const int ahead = (item >> 2) & 7;
  const int arowt = item & 3;
  const int abase = (apos * 8 + ahead) * 4;
  const int d0b   = half * 32;         // byte offset of this half's 16 dims (bf16)
  {
    const int qr  = abase + arowt;
    const int qsw = qksw(qr);
    uint2 qw[4];
#pragma unroll
    for (int u = 0; u < 4; u++)
      qw[u] = *(const uint2*)(lds + LDS_Q + qr * 64 + ((d0b + 8 * u) ^ qsw));
    float qf[16];
#pragma unroll
    for (int u = 0; u < 4; u++) {
      qf[4 * u + 0] = bflo(qw[u].x); qf[4 * u + 1] = bfhi(qw[u].x);
      qf[4 * u + 2] = bflo(qw[u].y); qf[4 * u + 3] = bfhi(qw[u].y);
    }
    float dots[4];
#pragma unroll
    for (int j = 0; j < 4; j++) {
      const int kr  = abase + j;
      const int ksw = qksw(kr);
      float s = 0.f;
#pragma unroll
      for (int u = 0; u < 4; u++) {
        uint2 kw = *(const uint2*)(lds + LDS_K + kr * 64 + ((d0b + 8 * u) ^ ksw));
        s += qf[4 * u + 0] * bflo(kw.x) + qf[4 * u + 1] * bfhi(kw.x)
           + qf[4 * u + 2] * bflo(kw.y) + qf[4 * u + 3] * bfhi(kw.y);
      }
      dots[j] = s;
    }
#pragma unroll
    for (int j = 0; j < 4; j++) {
      dots[j] += __shfl_xor(dots[j], 1);
      dots[j] += maskv<MASKI>(arowt, j);
    }
    const float mx = fmaxf(fmaxf(dots[0], dots[1]), fmaxf(dots[2], dots[3]));
    const float e0 = __expf(dots[0] - mx), e1 = __expf(dots[1] - mx);
    const float e2 = __expf(dots[2] - mx), e3 = __expf(dots[3] - mx);
    const float inv = 1.f / (e0 + e1 + e2 + e3);
    p0 = e0 * inv; p1 = e1 * inv; p2 = e2 * inv; p3 = e3 * inv;
  }
  __syncthreads();  // Q/K reads done; @32K..64K reusable for attnout frags
  phase_fence();

  // ---- PV (this thread's 16 dims) + write attnout hi/lo A-frags @32K/48K ----
  {
    const int dv0 = half * 64;  // byte offset of this half's 16 f32
    const int R   = apos * 4 + arowt;   // 0..31
    const int Rsw = (R & 15) << 4;
    const int s0 = (abase & 7) << 4;    // V row swizzles (abase..abase+3)
    const int s1 = ((abase + 1) & 7) << 4;
    const int s2 = ((abase + 2) & 7) << 4;
    const int s3 = ((abase + 3) & 7) << 4;
#pragma unroll
    for (int u = 0; u < 4; u++) {
      const int db = dv0 + 16 * u;
      float4 a0 = *(const float4*)(lds + (abase + 0) * 128 + (db ^ s0));
      float4 a1 = *(const float4*)(lds + (abase + 1) * 128 + (db ^ s1));
      float4 a2 = *(const float4*)(lds + (abase + 2) * 128 + (db ^ s2));
      float4 a3 = *(const float4*)(lds + (abase + 3) * 128 + (db ^ s3));
      float o0 = p0 * a0.x + p1 * a1.x + p2 * a2.x + p3 * a3.x;
      float o1 = p0 * a0.y + p1 * a1.y + p2 * a2.y + p3 * a3.y;
      float o2 = p0 * a0.z + p1 * a1.z + p2 * a2.z + p3 * a3.z;
      float o3 = p0 * a0.w + p1 * a1.w + p2 * a2.w + p3 * a3.w;
      const int col = ahead * 32 + half * 16 + u * 4;  // even
      u16 h0 = f2bf(o0), h1 = f2bf(o1), h2 = f2bf(o2), h3 = f2bf(o3);
      u16 l0 = f2bf(o0 - bf2f(h0)), l1 = f2bf(o1 - bf2f(h1));
      u16 l2 = f2bf(o2 - bf2f(h2)), l3 = f2bf(o3 - bf2f(h3));
      const int boA = (R * 512 + col * 2) ^ Rsw;
      const int boB = (R * 512 + (col + 2) * 2) ^ Rsw;
      *(u32*)(lds + LDS_Q + boA) = (u32)h0 | ((u32)h1 << 16);
      *(u32*)(lds + LDS_Q + boB) = (u32)h2 | ((u32)h3 << 16);
      *(u32*)(lds + LDS_K + boA) = (u32)l0 | ((u32)l1 << 16);
      *(u32*)(lds + LDS_K + boB) = (u32)l2 | ((u32)l3 << 16);
    }
  }
  __syncthreads();
  phase_fence();

  // ---- GEMM2: out(32x256) = attnout @ Wout^T (A-frags @32K/48K) ----
  f32x16 acc2;
#pragma unroll
  for (int i = 0; i < 16; i++) acc2[i] = 0.f;

#pragma unroll 4
  for (int ks = 0; ks < 16; ks++) {
    const int bo = (arow * 512 + (ks * 16 + kgrp) * 2) ^ ((arow & 15) << 4);
    bf16x8 ahi = *(const bf16x8*)(lds + LDS_Q + bo);
    bf16x8 alo = *(const bf16x8*)(lds + LDS_K + bo);
    const size_t o = (((size_t)wave * 16 + ks) * 64 + lane) * 8;
    bf16x8 bhi = *(const bf16x8*)(wo_hi + o);
    bf16x8 blo = *(const bf16x8*)(wo_lo + o);
    __builtin_amdgcn_s_setprio(1);
    acc2 = __builtin_amdgcn_mfma_f32_32x32x16_bf16(ahi, bhi, acc2, 0, 0, 0);
    acc2 = __builtin_amdgcn_mfma_f32_32x32x16_bf16(ahi, blo, acc2, 0, 0, 0);
    acc2 = __builtin_amdgcn_mfma_f32_32x32x16_bf16(alo, bhi, acc2, 0, 0, 0);
    __builtin_amdgcn_s_setprio(0);
  }
  return acc2;
  // Post-GEMM2, @0..32K is dead for ALL waves once this wave returns
  // (V reads ended at the pre-GEMM2 barrier), so the caller may write
  // z1 frags @0/16K without an extra barrier.
}

// ---------------- fused double-stage kernel ----------------
__global__ __launch_bounds__(512, 4)
void fused_kernel(const float* __restrict__ x, const float* __restrict__ y,
                  const float* __restrict__ g, float* __restrict__ outp,
                  const u16* __restrict__ wq0_hi, const u16* __restrict__ wq0_lo,
                  const u16* __restrict__ wo0_hi, const u16* __restrict__ wo0_lo,
                  const float* __restrict__ bout0,
                  const u16* __restrict__ wq1_hi, const u16* __restrict__ wq1_lo,
                  const u16* __restrict__ wo1_hi, const u16* __restrict__ wo1_lo,
                  const float* __restrict__ bout1) {
  extern __shared__ char lds[];
  const int tid  = threadIdx.x;
  const int lane = tid & 63;
  const int wave = tid >> 6;
  const int b    = blockIdx.y;
  const int pos0 = blockIdx.x * PTILE;

  // ---- stage z tile (32 rows x 256) into A_hi/A_lo frags @0/16K ----
  {
    const int r   = tid >> 4;          // 0..31
    const int cb  = (tid & 15) * 16;
    const int pos = pos0 + (r >> 2);
    const int tok = r & 3;
    const float* src;
    if (tok == 0)      src = x + ((size_t)b * NP + pos) * DIM;
    else if (tok == 1) src = y + ((size_t)b * NP + pos) * DIM;
    else if (tok == 2) src = g + b * DIM;
    else               src = g + (8 + b) * DIM;
    const int sw = (r & 15) << 4;
#pragma unroll
    for (int u = 0; u < 4; u++) {
      const int col = cb + u * 4;
      float4 v = *(const float4*)(src + col);
      u16 h0 = f2bf(v.x), h1 = f2bf(v.y), h2 = f2bf(v.z), h3 = f2bf(v.w);
      u16 l0 = f2bf(v.x - bf2f(h0)), l1 = f2bf(v.y - bf2f(h1));
      u16 l2 = f2bf(v.z - bf2f(h2)), l3 = f2bf(v.w - bf2f(h3));
      uint2 hw, lw;
      hw.x = (u32)h0 | ((u32)h1 << 16); hw.y = (u32)h2 | ((u32)h3 << 16);
      lw.x = (u32)l0 | ((u32)l1 << 16); lw.y = (u32)l2 | ((u32)l3 << 16);
      const int bo = (r * 512 + col * 2) ^ sw;
      *(uint2*)(lds + bo)           = hw;
      *(uint2*)(lds + LDS_ALO + bo) = lw;
    }
  }
  __syncthreads();
  phase_fence();

  // ---- stage 0 ----
  f32x16 a2 = stage_body<0>(lds, tid, lane, wave, wq0_hi, wq0_lo, wo0_hi, wo0_lo);
  phase_fence();

  // ---- z1 = out0 + bias0 -> A-frags @0/16K for stage 1 ----
  const int c  = wave * 32 + (lane & 31);
  const int rh = (lane >> 5) << 2;
  {
    const float bc = bout0[c];
#pragma unroll
    for (int i = 0; i < 16; i++) {
      const int r  = (i & 3) + ((i >> 2) << 3) + rh;
      const float v = a2[i] + bc;
      u16 h = f2bf(v);
      u16 l = f2bf(v - bf2f(h));
      const int bo = (r * 512 + c * 2) ^ ((r & 15) << 4);
      *(u16*)(lds + bo)           = h;
      *(u16*)(lds + LDS_ALO + bo) = l;
    }
  }
  __syncthreads();
  phase_fence();

  // ---- stage 1 ----
  f32x16 b2 = stage_body<1>(lds, tid, lane, wave, wq1_hi, wq1_lo, wo1_hi, wo1_lo);

  // ---- final epilogue: tok0 -> x1, tok1 -> y1 ----
  {
    const float bc = bout1[c];
    const size_t TOT = (size_t)NB * NP * DIM;
#pragma unroll
    for (int i = 0; i < 16; i++) {
      const int r   = (i & 3) + ((i >> 2) << 3) + rh;
      const int pos = pos0 + (r >> 2);
      const int tok = r & 3;
      const float v = b2[i] + bc;
      if (tok == 0)      outp[((size_t)b * NP + pos) * DIM + c] = v;
      else if (tok == 1) outp[TOT + ((size_t)b * NP + pos) * DIM + c] = v;
    }
  }
}

extern "C" void kernel_launch(void* const* d_in, const int* in_sizes, int n_in,
                              void* d_out, int out_size, void* d_ws, size_t ws_size,
                              hipStream_t stream) {
  const float* x     = (const float*)d_in[0];
  const float* y     = (const float*)d_in[1];
  const float* wqkv0 = (const float*)d_in[2];
  const float* wout0 = (const float*)d_in[3];
  const float* bout0 = (const float*)d_in[4];
  const float* wqkv1 = (const float*)d_in[5];
  const float* wout1 = (const float*)d_in[6];
  const float* bout1 = (const float*)d_in[7];

  float* part = (float*)d_ws;                        // 16*32*256 f32
  float* g    = part + (size_t)16 * 32 * DIM;        // 16*256 f32
  u16* w = (u16*)(g + 16 * DIM);
  u16* wq0_hi = w; w += 768 * 256;
  u16* wq0_lo = w; w += 768 * 256;
  u16* wo0_hi = w; w += 256 * 256;
  u16* wo0_lo = w; w += 256 * 256;
  u16* wq1_hi = w; w += 768 * 256;
  u16* wq1_lo = w; w += 768 * 256;
  u16* wo1_hi = w; w += 256 * 256;
  u16* wo1_lo = w; w += 256 * 256;

  mean_partial<<<dim3(32, 16), dim3(256), 0, stream>>>(x, y, part);
  mean_final<<<dim3(16), dim3(256), 0, stream>>>(part, g);

  pack_w<<<dim3(24, 16), dim3(64), 0, stream>>>(wqkv0, wq0_hi, wq0_lo, 1);
  pack_w<<<dim3(8, 16),  dim3(64), 0, stream>>>(wout0, wo0_hi, wo0_lo, 0);
  pack_w<<<dim3(24, 16), dim3(64), 0, stream>>>(wqkv1, wq1_hi, wq1_lo, 1);
  pack_w<<<dim3(8, 16),  dim3(64), 0, stream>>>(wout1, wo1_hi, wo1_lo, 0);

  fused_kernel<<<dim3(NP / PTILE, NB), dim3(512), LDS_SZ, stream>>>(
      x, y, g, (float*)d_out,
      wq0_hi, wq0_lo, wo0_hi, wo0_lo, bout0,
      wq1_hi, wq1_lo, wo1_hi, wo1_lo, bout1);
}

// Round 7
// 409.034 us; speedup vs baseline: 1.5769x; 1.1045x over previous
//
#include <hip/hip_runtime.h>

typedef unsigned short u16;
typedef unsigned int   u32;
typedef short bf16x8 __attribute__((ext_vector_type(8)));
typedef float f32x16 __attribute__((ext_vector_type(16)));

#define NB    8
#define NP    3136
#define DIM   256
#define PTILE 8
#define NEGM  (-100.0f)
#define QKSCALE 0.17677669529663687f

// LDS (64 KiB), regions reused across barrier-separated phases:
//  @0      A_hi (16K) } -> V f32 col-major [h][d][tok] (32K) -> z1_hi/z1_lo
//  @16384  A_lo (16K) }
//  @32768  Q bf16 col-major [h][d][tok] (16K) -> attnout_hi frags (16K)
//  @49152  K bf16 col-major [h][d][tok] (16K) -> attnout_lo frags (16K)
#define LDS_ALO 16384
#define LDS_Q   32768
#define LDS_K   49152
#define LDS_SZ  65536

__device__ __forceinline__ float bflo(u32 w) { return __uint_as_float(w << 16); }
__device__ __forceinline__ float bfhi(u32 w) { return __uint_as_float(w & 0xffff0000u); }

// packed f32x2 -> bf16x2 (RTNE), 1 VALU op
__device__ __forceinline__ u32 cvt_pk(float a, float b) {
  u32 r;
  asm("v_cvt_pk_bf16_f32 %0, %1, %2" : "=v"(r) : "v"(a), "v"(b));
  return r;
}

__device__ __forceinline__ void phase_fence() {
  __builtin_amdgcn_sched_barrier(0);
}

template<int MASKI>
__device__ __forceinline__ float maskv(int i, int j) {
  if (MASKI == 0) return ((i ^ j) == 3) ? NEGM : 0.f;
  return (i >= 2 || ((i ^ j) & 1)) ? NEGM : 0.f;
}

// ---------------- global-token means (deterministic 2-pass) ----------------
__global__ void mean_partial(const float* __restrict__ x,
                             const float* __restrict__ y,
                             float* __restrict__ part) {
  const int chunk = blockIdx.x;
  const int ab = blockIdx.y;
  const int b = ab & 7;
  const float* src = (ab >> 3) ? y : x;
  const int d = threadIdx.x;
  float s = 0.f;
  const int p0 = chunk * 98;  // 3136 = 32*98
  for (int i = 0; i < 98; i++)
    s += src[((size_t)b * NP + p0 + i) * DIM + d];
  part[((size_t)ab * 32 + chunk) * DIM + d] = s;
}

__global__ void mean_final(const float* __restrict__ part, float* __restrict__ g) {
  const int ab = blockIdx.x;
  const int d = threadIdx.x;
  float s = 0.f;
  for (int c = 0; c < 32; c++) s += part[((size_t)ab * 32 + c) * DIM + d];
  g[ab * DIM + d] = s * (1.0f / 3136.0f);
}

// ---------------- W -> packed hi/lo bf16 fragments ----------------
// Fragment order: [(ntile*16 + ks)*64 + lane]*8 ; lane holds B[n][k0..k0+7].
// is_qkv: pre-scale the Q output columns (n < 256) by QKSCALE.
__global__ void pack_w(const float* __restrict__ W, u16* __restrict__ hi,
                       u16* __restrict__ lo, int is_qkv) {
  const int nt = blockIdx.x, ks = blockIdx.y, lane = threadIdx.x;
  const int n  = nt * 32 + (lane & 31);
  const int k0 = ks * 16 + ((lane >> 5) << 3);
  const float scale = (is_qkv && n < 256) ? QKSCALE : 1.0f;
  const float* src = W + (size_t)n * 256 + k0;
  const size_t o = (((size_t)nt * 16 + ks) * 64 + lane) * 8;
#pragma unroll
  for (int j = 0; j < 8; j++) {
    float v = src[j] * scale;
    u32 wh = cvt_pk(v, v);
    float l = v - bflo(wh);
    u32 wl = cvt_pk(l, l);
    hi[o + j] = (u16)wh;
    lo[o + j] = (u16)wl;
  }
}

// ---------------- per-stage body ----------------
// Entry: A-frags (hi@0, lo@16K) staged, barrier passed.
// Exit: returns GEMM2 acc (out tile cols wave*32..wave*32+31); all LDS dead.
template<int MASKI>
__device__ __forceinline__ f32x16 stage_body(
    char* lds, int tid, int lane, int wave,
    const u16* __restrict__ wq_hi, const u16* __restrict__ wq_lo,
    const u16* __restrict__ wo_hi, const u16* __restrict__ wo_lo) {

  const int arow = lane & 31;
  const int kgrp = (lane >> 5) << 3;
  const int cl   = lane & 31;
  const int rh5  = lane >> 5;        // 0/1

  // ---- GEMM1: wave w computes tiles {w}=Q, {8+w}=K, {16+w}=V (head=w) ----
  // Q/K scatter immediately to col-major [h][d][tok] with packed b64 writes;
  // V acc held across the barrier, then scattered col-major f32.
  f32x16 accV;
#pragma unroll 1
  for (int t = 0; t < 3; t++) {
    f32x16 acc;
#pragma unroll
    for (int i = 0; i < 16; i++) acc[i] = 0.f;
    const int nt = t * 8 + wave;
#pragma unroll 4
    for (int ks = 0; ks < 16; ks++) {
      const int bo = (arow * 512 + (ks * 16 + kgrp) * 2) ^ ((arow & 15) << 4);
      bf16x8 ahi = *(const bf16x8*)(lds + bo);
      bf16x8 alo = *(const bf16x8*)(lds + LDS_ALO + bo);
      const size_t o = (((size_t)nt * 16 + ks) * 64 + lane) * 8;
      bf16x8 bhi = *(const bf16x8*)(wq_hi + o);
      bf16x8 blo = *(const bf16x8*)(wq_lo + o);
      __builtin_amdgcn_s_setprio(1);
      acc = __builtin_amdgcn_mfma_f32_32x32x16_bf16(ahi, bhi, acc, 0, 0, 0);
      acc = __builtin_amdgcn_mfma_f32_32x32x16_bf16(ahi, blo, acc, 0, 0, 0);
      acc = __builtin_amdgcn_mfma_f32_32x32x16_bf16(alo, bhi, acc, 0, 0, 0);
      __builtin_amdgcn_s_setprio(0);
    }
    if (t == 2) {
      accV = acc;
    } else {
      // acc[4g+k] = value at (tok = k + 8g + rh5*4, d = cl); 4-tok quads pack
      // into one b64 at Qc[h=wave][d=cl][pos_g*4], XOR ((d>>2)&7)<<3.
      const int base = (t == 0 ? LDS_Q : LDS_K) + wave * 2048 + cl * 64;
      const int sw = ((cl >> 2) & 7) << 3;
#pragma unroll
      for (int g = 0; g < 4; g++) {
        uint2 wv;
        wv.x = cvt_pk(acc[4 * g + 0], acc[4 * g + 1]);
        wv.y = cvt_pk(acc[4 * g + 2], acc[4 * g + 3]);
        const int pg = rh5 + 2 * g;
        *(uint2*)(lds + base + ((pg * 8) ^ sw)) = wv;
      }
    }
  }
  __syncthreads();  // all waves done reading A region (@0..32K)
  phase_fence();

  // ---- scatter V f32 col-major [h=wave][d=cl][tok], XOR ((d>>2)&7)<<4 ----
  {
    const int vbase = wave * 4096 + cl * 128;
    const int swv = ((cl >> 2) & 7) << 4;
#pragma unroll
    for (int p = 0; p < 8; p++) {
      const int i = 2 * p;
      const int r = (i & 3) + ((i >> 2) << 3) + rh5 * 4;  // even tok
      float2 vv;
      vv.x = accV[i];
      vv.y = accV[i + 1];
      *(float2*)(lds + vbase + ((r * 4) ^ swv)) = vv;
    }
  }
  __syncthreads();
  phase_fence();

  // ---- attention: wave = pos-group, head = lane>>3, dgrp = lane&7 (4 d's) ----
  const int dgrp  = lane & 7;
  const int ahead = lane >> 3;
  float p[4][4];
  {
    uint2 qw[4], kw[4];
    const int qoff = ahead * 2048 + dgrp * 256 + ((wave * 8) ^ (dgrp << 3));
#pragma unroll
    for (int dd = 0; dd < 4; dd++) {
      qw[dd] = *(const uint2*)(lds + LDS_Q + qoff + dd * 64);
      kw[dd] = *(const uint2*)(lds + LDS_K + qoff + dd * 64);
    }
    float dots[4][4];
#pragma unroll
    for (int i = 0; i < 4; i++)
#pragma unroll
      for (int j = 0; j < 4; j++) dots[i][j] = 0.f;
#pragma unroll
    for (int dd = 0; dd < 4; dd++) {
      const float q0 = bflo(qw[dd].x), q1 = bfhi(qw[dd].x);
      const float q2 = bflo(qw[dd].y), q3 = bfhi(qw[dd].y);
      const float k0 = bflo(kw[dd].x), k1 = bfhi(kw[dd].x);
      const float k2 = bflo(kw[dd].y), k3 = bfhi(kw[dd].y);
      dots[0][0] += q0 * k0; dots[0][1] += q0 * k1; dots[0][2] += q0 * k2; dots[0][3] += q0 * k3;
      dots[1][0] += q1 * k0; dots[1][1] += q1 * k1; dots[1][2] += q1 * k2; dots[1][3] += q1 * k3;
      dots[2][0] += q2 * k0; dots[2][1] += q2 * k1; dots[2][2] += q2 * k2; dots[2][3] += q2 * k3;
      dots[3][0] += q3 * k0; dots[3][1] += q3 * k1; dots[3][2] += q3 * k2; dots[3][3] += q3 * k3;
    }
    // reduce over the 8 d-groups (lanes xor 1,2,4)
#pragma unroll
    for (int i = 0; i < 4; i++)
#pragma unroll
      for (int j = 0; j < 4; j++) {
        float s = dots[i][j];
        s += __shfl_xor(s, 1);
        s += __shfl_xor(s, 2);
        s += __shfl_xor(s, 4);
        dots[i][j] = s;
      }
    // masked softmax per row (redundant across the 8 lanes of the group)
#pragma unroll
    for (int i = 0; i < 4; i++) {
      const float d0 = dots[i][0] + maskv<MASKI>(i, 0);
      const float d1 = dots[i][1] + maskv<MASKI>(i, 1);
      const float d2 = dots[i][2] + maskv<MASKI>(i, 2);
      const float d3 = dots[i][3] + maskv<MASKI>(i, 3);
      const float mx = fmaxf(fmaxf(d0, d1), fmaxf(d2, d3));
      const float e0 = __expf(d0 - mx), e1 = __expf(d1 - mx);
      const float e2 = __expf(d2 - mx), e3 = __expf(d3 - mx);
      const float inv = 1.f / (e0 + e1 + e2 + e3);
      p[i][0] = e0 * inv; p[i][1] = e1 * inv;
      p[i][2] = e2 * inv; p[i][3] = e3 * inv;
    }
  }
  __syncthreads();  // Q/K reads done; @32K..64K reusable for attnout frags
  phase_fence();

  // ---- PV (4 dims per thread) + packed attnout hi/lo A-frag writes ----
  {
    const int voff = ahead * 4096 + dgrp * 512 + ((wave * 16) ^ (dgrp << 4));
    const float4 v0 = *(const float4*)(lds + voff + 0);    // dim dgrp*4+0, toks 0..3
    const float4 v1 = *(const float4*)(lds + voff + 128);
    const float4 v2 = *(const float4*)(lds + voff + 256);
    const float4 v3 = *(const float4*)(lds + voff + 384);
#pragma unroll
    for (int ti = 0; ti < 4; ti++) {
      const float o0 = p[ti][0] * v0.x + p[ti][1] * v0.y + p[ti][2] * v0.z + p[ti][3] * v0.w;
      const float o1 = p[ti][0] * v1.x + p[ti][1] * v1.y + p[ti][2] * v1.z + p[ti][3] * v1.w;
      const float o2 = p[ti][0] * v2.x + p[ti][1] * v2.y + p[ti][2] * v2.z + p[ti][3] * v2.w;
      const float o3 = p[ti][0] * v3.x + p[ti][1] * v3.y + p[ti][2] * v3.z + p[ti][3] * v3.w;
      const int R = wave * 4 + ti;
      const u32 h0 = cvt_pk(o0, o1), h1 = cvt_pk(o2, o3);
      const float l0 = o0 - bflo(h0), l1 = o1 - bfhi(h0);
      const float l2 = o2 - bflo(h1), l3 = o3 - bfhi(h1);
      const u32 g0 = cvt_pk(l0, l1), g1 = cvt_pk(l2, l3);
      const int bo = (R * 512 + ahead * 64 + dgrp * 8) ^ ((R & 15) << 4);
      uint2 hw; hw.x = h0; hw.y = h1;
      uint2 lw; lw.x = g0; lw.y = g1;
      *(uint2*)(lds + LDS_Q + bo) = hw;
      *(uint2*)(lds + LDS_K + bo) = lw;
    }
  }
  __syncthreads();
  phase_fence();

  // ---- GEMM2: out(32x256) = attnout @ Wout^T (A-frags @32K/48K) ----
  f32x16 acc2;
#pragma unroll
  for (int i = 0; i < 16; i++) acc2[i] = 0.f;

#pragma unroll 4
  for (int ks = 0; ks < 16; ks++) {
    const int bo = (arow * 512 + (ks * 16 + kgrp) * 2) ^ ((arow & 15) << 4);
    bf16x8 ahi = *(const bf16x8*)(lds + LDS_Q + bo);
    bf16x8 alo = *(const bf16x8*)(lds + LDS_K + bo);
    const size_t o = (((size_t)wave * 16 + ks) * 64 + lane) * 8;
    bf16x8 bhi = *(const bf16x8*)(wo_hi + o);
    bf16x8 blo = *(const bf16x8*)(wo_lo + o);
    __builtin_amdgcn_s_setprio(1);
    acc2 = __builtin_amdgcn_mfma_f32_32x32x16_bf16(ahi, bhi, acc2, 0, 0, 0);
    acc2 = __builtin_amdgcn_mfma_f32_32x32x16_bf16(ahi, blo, acc2, 0, 0, 0);
    acc2 = __builtin_amdgcn_mfma_f32_32x32x16_bf16(alo, bhi, acc2, 0, 0, 0);
    __builtin_amdgcn_s_setprio(0);
  }
  return acc2;
  // Post-GEMM2, @0..32K (V) is dead for all waves (V reads ended at the
  // pre-GEMM2 barrier), so the caller may write z1 frags there directly.
}

// ---------------- fused double-stage kernel ----------------
__global__ __launch_bounds__(512, 4)
void fused_kernel(const float* __restrict__ x, const float* __restrict__ y,
                  const float* __restrict__ g, float* __restrict__ outp,
                  const u16* __restrict__ wq0_hi, const u16* __restrict__ wq0_lo,
                  const u16* __restrict__ wo0_hi, const u16* __restrict__ wo0_lo,
                  const float* __restrict__ bout0,
                  const u16* __restrict__ wq1_hi, const u16* __restrict__ wq1_lo,
                  const u16* __restrict__ wo1_hi, const u16* __restrict__ wo1_lo,
                  const float* __restrict__ bout1) {
  extern __shared__ char lds[];
  const int tid  = threadIdx.x;
  const int lane = tid & 63;
  const int wave = tid >> 6;
  const int b    = blockIdx.y;
  const int pos0 = blockIdx.x * PTILE;

  // ---- stage z tile (32 rows x 256) into A_hi/A_lo frags @0/16K ----
  {
    const int r   = tid >> 4;          // 0..31
    const int cb  = (tid & 15) * 16;
    const int pos = pos0 + (r >> 2);
    const int tok = r & 3;
    const float* src;
    if (tok == 0)      src = x + ((size_t)b * NP + pos) * DIM;
    else if (tok == 1) src = y + ((size_t)b * NP + pos) * DIM;
    else if (tok == 2) src = g + b * DIM;
    else               src = g + (8 + b) * DIM;
    const int sw = (r & 15) << 4;
#pragma unroll
    for (int u = 0; u < 4; u++) {
      const int col = cb + u * 4;
      float4 v = *(const float4*)(src + col);
      uint2 hw, lw;
      hw.x = cvt_pk(v.x, v.y);
      hw.y = cvt_pk(v.z, v.w);
      const float lx = v.x - bflo(hw.x), ly = v.y - bfhi(hw.x);
      const float lz = v.z - bflo(hw.y), lww = v.w - bfhi(hw.y);
      lw.x = cvt_pk(lx, ly);
      lw.y = cvt_pk(lz, lww);
      const int bo = (r * 512 + col * 2) ^ sw;
      *(uint2*)(lds + bo)           = hw;
      *(uint2*)(lds + LDS_ALO + bo) = lw;
    }
  }
  __syncthreads();
  phase_fence();

  // ---- stage 0 ----
  f32x16 a2 = stage_body<0>(lds, tid, lane, wave, wq0_hi, wq0_lo, wo0_hi, wo0_lo);
  phase_fence();

  // ---- z1 = out0 + bias0 -> A-frags @0/16K for stage 1 ----
  const int c  = wave * 32 + (lane & 31);
  const int rh = (lane >> 5) << 2;
  {
    const float bc = bout0[c];
#pragma unroll
    for (int i = 0; i < 16; i++) {
      const int r  = (i & 3) + ((i >> 2) << 3) + rh;
      const float v = a2[i] + bc;
      const u32 wh = cvt_pk(v, v);
      const float l = v - bflo(wh);
      const u32 wl = cvt_pk(l, l);
      const int bo = (r * 512 + c * 2) ^ ((r & 15) << 4);
      *(u16*)(lds + bo)           = (u16)wh;
      *(u16*)(lds + LDS_ALO + bo) = (u16)wl;
    }
  }
  __syncthreads();
  phase_fence();

  // ---- stage 1 ----
  f32x16 b2 = stage_body<1>(lds, tid, lane, wave, wq1_hi, wq1_lo, wo1_hi, wo1_lo);

  // ---- final epilogue: tok0 -> x1, tok1 -> y1 ----
  {
    const float bc = bout1[c];
    const size_t TOT = (size_t)NB * NP * DIM;
#pragma unroll
    for (int i = 0; i < 16; i++) {
      const int r   = (i & 3) + ((i >> 2) << 3) + rh;
      const int pos = pos0 + (r >> 2);
      const int tok = r & 3;
      const float v = b2[i] + bc;
      if (tok == 0)      outp[((size_t)b * NP + pos) * DIM + c] = v;
      else if (tok == 1) outp[TOT + ((size_t)b * NP + pos) * DIM + c] = v;
    }
  }
}

extern "C" void kernel_launch(void* const* d_in, const int* in_sizes, int n_in,
                              void* d_out, int out_size, void* d_ws, size_t ws_size,
                              hipStream_t stream) {
  const float* x     = (const float*)d_in[0];
  const float* y     = (const float*)d_in[1];
  const float* wqkv0 = (const float*)d_in[2];
  const float* wout0 = (const float*)d_in[3];
  const float* bout0 = (const float*)d_in[4];
  const float* wqkv1 = (const float*)d_in[5];
  const float* wout1 = (const float*)d_in[6];
  const float* bout1 = (const float*)d_in[7];

  float* part = (float*)d_ws;                        // 16*32*256 f32
  float* g    = part + (size_t)16 * 32 * DIM;        // 16*256 f32
  u16* w = (u16*)(g + 16 * DIM);
  u16* wq0_hi = w; w += 768 * 256;
  u16* wq0_lo = w; w += 768 * 256;
  u16* wo0_hi = w; w += 256 * 256;
  u16* wo0_lo = w; w += 256 * 256;
  u16* wq1_hi = w; w += 768 * 256;
  u16* wq1_lo = w; w += 768 * 256;
  u16* wo1_hi = w; w += 256 * 256;
  u16* wo1_lo = w; w += 256 * 256;

  mean_partial<<<dim3(32, 16), dim3(256), 0, stream>>>(x, y, part);
  mean_final<<<dim3(16), dim3(256), 0, stream>>>(part, g);

  pack_w<<<dim3(24, 16), dim3(64), 0, stream>>>(wqkv0, wq0_hi, wq0_lo, 1);
  pack_w<<<dim3(8, 16),  dim3(64), 0, stream>>>(wout0, wo0_hi, wo0_lo, 0);
  pack_w<<<dim3(24, 16), dim3(64), 0, stream>>>(wqkv1, wq1_hi, wq1_lo, 1);
  pack_w<<<dim3(8, 16),  dim3(64), 0, stream>>>(wout1, wo1_hi, wo1_lo, 0);

  fused_kernel<<<dim3(NP / PTILE, NB), dim3(512), LDS_SZ, stream>>>(
      x, y, g, (float*)d_out,
      wq0_hi, wq0_lo, wo0_hi, wo0_lo, bout0,
      wq1_hi, wq1_lo, wo1_hi, wo1_lo, bout1);
}

// Round 8
// 407.944 us; speedup vs baseline: 1.5811x; 1.0027x over previous
//
#include <hip/hip_runtime.h>

typedef unsigned short u16;
typedef unsigned int   u32;
typedef short bf16x8 __attribute__((ext_vector_type(8)));
typedef float f32x16 __attribute__((ext_vector_type(16)));

#define NB    8
#define NP    3136
#define DIM   256
#define PTILE 8
#define NEGM  (-100.0f)
#define QKSCALE 0.17677669529663687f

// LDS (64 KiB), ping-pong between two 32K halves:
// stage0: A-frags @0/16K; Q/K col-major @32K/48K; V f32 @0..32K (A dead);
//         attnout frags @32K/48K (QK dead).
// stage1: A = attnout0 @32K/48K; Q/K @0/16K; V @32K..64K (A dead);
//         attnout1 @0/16K -> GEMM2 reads there.
#define LDS_SZ  65536

__device__ __forceinline__ float bflo(u32 w) { return __uint_as_float(w << 16); }
__device__ __forceinline__ float bfhi(u32 w) { return __uint_as_float(w & 0xffff0000u); }

// packed f32x2 -> bf16x2 (RTNE), 1 VALU op
__device__ __forceinline__ u32 cvt_pk(float a, float b) {
  u32 r;
  asm("v_cvt_pk_bf16_f32 %0, %1, %2" : "=v"(r) : "v"(a), "v"(b));
  return r;
}

__device__ __forceinline__ void phase_fence() {
  __builtin_amdgcn_sched_barrier(0);
}

template<int MASKI>
__device__ __forceinline__ float maskv(int i, int j) {
  if (MASKI == 0) return ((i ^ j) == 3) ? NEGM : 0.f;
  return (i >= 2 || ((i ^ j) & 1)) ? NEGM : 0.f;
}

// ---------------- global-token means (deterministic 2-pass) ----------------
__global__ void mean_partial(const float* __restrict__ x,
                             const float* __restrict__ y,
                             float* __restrict__ part) {
  const int chunk = blockIdx.x;
  const int ab = blockIdx.y;
  const int b = ab & 7;
  const float* src = (ab >> 3) ? y : x;
  const int d = threadIdx.x;
  float s = 0.f;
  const int p0 = chunk * 98;  // 3136 = 32*98
  for (int i = 0; i < 98; i++)
    s += src[((size_t)b * NP + p0 + i) * DIM + d];
  part[((size_t)ab * 32 + chunk) * DIM + d] = s;
}

__global__ void mean_final(const float* __restrict__ part, float* __restrict__ g) {
  const int ab = blockIdx.x;
  const int d = threadIdx.x;
  float s = 0.f;
  for (int c = 0; c < 32; c++) s += part[((size_t)ab * 32 + c) * DIM + d];
  g[ab * DIM + d] = s * (1.0f / 3136.0f);
}

// ---------------- W_combo = Wqkv1 . Wout0  (768x256, f32) ----------------
__global__ void combo_w(const float* __restrict__ Wq1, const float* __restrict__ Wo0,
                        float* __restrict__ Wc) {
  const int e  = threadIdx.x;
  const int n0 = blockIdx.x * 8;
  float acc[8] = {0.f, 0.f, 0.f, 0.f, 0.f, 0.f, 0.f, 0.f};
  for (int d = 0; d < 256; d++) {
    const float w0 = Wo0[d * 256 + e];
#pragma unroll
    for (int i = 0; i < 8; i++)
      acc[i] += Wq1[(n0 + i) * 256 + d] * w0;
  }
#pragma unroll
  for (int i = 0; i < 8; i++) Wc[(n0 + i) * 256 + e] = acc[i];
}

// ---------------- bq' = Wqkv1 . bout0 (768, f32; Q rows pre-scaled) --------
__global__ void combo_b(const float* __restrict__ Wq1, const float* __restrict__ b0,
                        float* __restrict__ bq) {
  const int n = blockIdx.x * 256 + threadIdx.x;
  float s = 0.f;
  for (int d = 0; d < 256; d += 4) {
    const float4 w = *(const float4*)(Wq1 + (size_t)n * 256 + d);
    const float4 b = *(const float4*)(b0 + d);
    s += w.x * b.x + w.y * b.y + w.z * b.z + w.w * b.w;
  }
  bq[n] = (n < 256) ? s * QKSCALE : s;
}

// ---------------- W -> packed hi/lo bf16 fragments ----------------
// Fragment order: [(ntile*16 + ks)*64 + lane]*8 ; lane holds B[n][k0..k0+7].
// is_qkv: pre-scale the Q output columns (n < 256) by QKSCALE.
__global__ void pack_w(const float* __restrict__ W, u16* __restrict__ hi,
                       u16* __restrict__ lo, int is_qkv) {
  const int nt = blockIdx.x, ks = blockIdx.y, lane = threadIdx.x;
  const int n  = nt * 32 + (lane & 31);
  const int k0 = ks * 16 + ((lane >> 5) << 3);
  const float scale = (is_qkv && n < 256) ? QKSCALE : 1.0f;
  const float* src = W + (size_t)n * 256 + k0;
  const size_t o = (((size_t)nt * 16 + ks) * 64 + lane) * 8;
#pragma unroll
  for (int j = 0; j < 8; j++) {
    float v = src[j] * scale;
    u32 wh = cvt_pk(v, v);
    float l = v - bflo(wh);
    u32 wl = cvt_pk(l, l);
    hi[o + j] = (u16)wh;
    lo[o + j] = (u16)wl;
  }
}

// ---------------- per-stage GEMM1 + attention ----------------
// Entry: A-frags (hi@ABASE, lo@ABASE+16K) staged, barrier passed.
// Exit (after internal barrier): attnout hi/lo A-frags @QKB / QKB+16K,
// where QKB = ABASE ^ 32768. All other LDS dead.
template<int MASKI, bool QB>
__device__ __forceinline__ void stage_attn(
    char* lds, const int ABASE, int tid, int lane, int wave,
    const u16* __restrict__ w_hi, const u16* __restrict__ w_lo,
    const float* __restrict__ qbias) {

  const int QKB  = ABASE ^ 32768;
  const int arow = lane & 31;
  const int kgrp = (lane >> 5) << 3;
  const int cl   = lane & 31;
  const int rh5  = lane >> 5;        // 0/1

  // ---- GEMM1: wave w computes tiles {w}=Q, {8+w}=K, {16+w}=V (head=w) ----
  f32x16 accV;
#pragma unroll 1
  for (int t = 0; t < 3; t++) {
    f32x16 acc;
#pragma unroll
    for (int i = 0; i < 16; i++) acc[i] = 0.f;
    const int nt = t * 8 + wave;
#pragma unroll 4
    for (int ks = 0; ks < 16; ks++) {
      const int bo = ABASE + ((arow * 512 + (ks * 16 + kgrp) * 2) ^ ((arow & 15) << 4));
      bf16x8 ahi = *(const bf16x8*)(lds + bo);
      bf16x8 alo = *(const bf16x8*)(lds + 16384 + bo);
      const size_t o = (((size_t)nt * 16 + ks) * 64 + lane) * 8;
      bf16x8 bhi = *(const bf16x8*)(w_hi + o);
      bf16x8 blo = *(const bf16x8*)(w_lo + o);
      __builtin_amdgcn_s_setprio(1);
      acc = __builtin_amdgcn_mfma_f32_32x32x16_bf16(ahi, bhi, acc, 0, 0, 0);
      acc = __builtin_amdgcn_mfma_f32_32x32x16_bf16(ahi, blo, acc, 0, 0, 0);
      acc = __builtin_amdgcn_mfma_f32_32x32x16_bf16(alo, bhi, acc, 0, 0, 0);
      __builtin_amdgcn_s_setprio(0);
    }
    const float qb = QB ? qbias[t * 256 + wave * 32 + cl] : 0.f;
    if (QB) {
#pragma unroll
      for (int i = 0; i < 16; i++) acc[i] += qb;
    }
    if (t == 2) {
      accV = acc;
    } else {
      // col-major [h=wave][d=cl][tok], packed b64, XOR ((d>>2)&7)<<3
      const int base = (t == 0 ? QKB : QKB + 16384) + wave * 2048 + cl * 64;
      const int sw = ((cl >> 2) & 7) << 3;
#pragma unroll
      for (int g = 0; g < 4; g++) {
        uint2 wv;
        wv.x = cvt_pk(acc[4 * g + 0], acc[4 * g + 1]);
        wv.y = cvt_pk(acc[4 * g + 2], acc[4 * g + 3]);
        const int pg = rh5 + 2 * g;
        *(uint2*)(lds + base + ((pg * 8) ^ sw)) = wv;
      }
    }
  }
  __syncthreads();  // all waves done reading A region
  phase_fence();

  // ---- V scatter (f32 col-major @ABASE, XOR ((d>>2)&7)<<4) ∥ dots ----
  {
    const int vbase = ABASE + wave * 4096 + cl * 128;
    const int swv = ((cl >> 2) & 7) << 4;
#pragma unroll
    for (int p = 0; p < 8; p++) {
      const int i = 2 * p;
      const int r = (i & 3) + ((i >> 2) << 3) + rh5 * 4;  // even tok
      float2 vv;
      vv.x = accV[i];
      vv.y = accV[i + 1];
      *(float2*)(lds + vbase + ((r * 4) ^ swv)) = vv;
    }
  }

  // ---- attention dots: wave = pos-group, head = lane>>3, dgrp = lane&7 ----
  const int dgrp  = lane & 7;
  const int ahead = lane >> 3;
  float p[4][4];
  {
    uint2 qw[4], kw[4];
    const int qoff = ahead * 2048 + dgrp * 256 + ((wave * 8) ^ (dgrp << 3));
#pragma unroll
    for (int dd = 0; dd < 4; dd++) {
      qw[dd] = *(const uint2*)(lds + QKB + qoff + dd * 64);
      kw[dd] = *(const uint2*)(lds + QKB + 16384 + qoff + dd * 64);
    }
    float dots[4][4];
#pragma unroll
    for (int i = 0; i < 4; i++)
#pragma unroll
      for (int j = 0; j < 4; j++) dots[i][j] = 0.f;
#pragma unroll
    for (int dd = 0; dd < 4; dd++) {
      const float q0 = bflo(qw[dd].x), q1 = bfhi(qw[dd].x);
      const float q2 = bflo(qw[dd].y), q3 = bfhi(qw[dd].y);
      const float k0 = bflo(kw[dd].x), k1 = bfhi(kw[dd].x);
      const float k2 = bflo(kw[dd].y), k3 = bfhi(kw[dd].y);
      dots[0][0] += q0 * k0; dots[0][1] += q0 * k1; dots[0][2] += q0 * k2; dots[0][3] += q0 * k3;
      dots[1][0] += q1 * k0; dots[1][1] += q1 * k1; dots[1][2] += q1 * k2; dots[1][3] += q1 * k3;
      dots[2][0] += q2 * k0; dots[2][1] += q2 * k1; dots[2][2] += q2 * k2; dots[2][3] += q2 * k3;
      dots[3][0] += q3 * k0; dots[3][1] += q3 * k1; dots[3][2] += q3 * k2; dots[3][3] += q3 * k3;
    }
#pragma unroll
    for (int i = 0; i < 4; i++)
#pragma unroll
      for (int j = 0; j < 4; j++) {
        float s = dots[i][j];
        s += __shfl_xor(s, 1);
        s += __shfl_xor(s, 2);
        s += __shfl_xor(s, 4);
        dots[i][j] = s;
      }
#pragma unroll
    for (int i = 0; i < 4; i++) {
      const float d0 = dots[i][0] + maskv<MASKI>(i, 0);
      const float d1 = dots[i][1] + maskv<MASKI>(i, 1);
      const float d2 = dots[i][2] + maskv<MASKI>(i, 2);
      const float d3 = dots[i][3] + maskv<MASKI>(i, 3);
      const float mx = fmaxf(fmaxf(d0, d1), fmaxf(d2, d3));
      const float e0 = __expf(d0 - mx), e1 = __expf(d1 - mx);
      const float e2 = __expf(d2 - mx), e3 = __expf(d3 - mx);
      const float inv = 1.f / (e0 + e1 + e2 + e3);
      p[i][0] = e0 * inv; p[i][1] = e1 * inv;
      p[i][2] = e2 * inv; p[i][3] = e3 * inv;
    }
  }
  __syncthreads();  // V writes visible; all Q/K reads done
  phase_fence();

  // ---- PV (4 dims/thread) + attnout hi/lo A-frags @QKB / QKB+16K ----
  {
    const int voff = ABASE + ahead * 4096 + dgrp * 512 + ((wave * 16) ^ (dgrp << 4));
    const float4 v0 = *(const float4*)(lds + voff + 0);
    const float4 v1 = *(const float4*)(lds + voff + 128);
    const float4 v2 = *(const float4*)(lds + voff + 256);
    const float4 v3 = *(const float4*)(lds + voff + 384);
#pragma unroll
    for (int ti = 0; ti < 4; ti++) {
      const float o0 = p[ti][0] * v0.x + p[ti][1] * v0.y + p[ti][2] * v0.z + p[ti][3] * v0.w;
      const float o1 = p[ti][0] * v1.x + p[ti][1] * v1.y + p[ti][2] * v1.z + p[ti][3] * v1.w;
      const float o2 = p[ti][0] * v2.x + p[ti][1] * v2.y + p[ti][2] * v2.z + p[ti][3] * v2.w;
      const float o3 = p[ti][0] * v3.x + p[ti][1] * v3.y + p[ti][2] * v3.z + p[ti][3] * v3.w;
      const int R = wave * 4 + ti;
      const u32 h0 = cvt_pk(o0, o1), h1 = cvt_pk(o2, o3);
      const float l0 = o0 - bflo(h0), l1 = o1 - bfhi(h0);
      const float l2 = o2 - bflo(h1), l3 = o3 - bfhi(h1);
      const u32 g0 = cvt_pk(l0, l1), g1 = cvt_pk(l2, l3);
      const int bo = QKB + ((R * 512 + ahead * 64 + dgrp * 8) ^ ((R & 15) << 4));
      uint2 hw; hw.x = h0; hw.y = h1;
      uint2 lw; lw.x = g0; lw.y = g1;
      *(uint2*)(lds + bo)         = hw;
      *(uint2*)(lds + 16384 + bo) = lw;
    }
  }
  __syncthreads();  // attnout ready as next A
  phase_fence();
}

// ---------------- fused double-stage kernel ----------------
__global__ __launch_bounds__(512, 4)
void fused_kernel(const float* __restrict__ x, const float* __restrict__ y,
                  const float* __restrict__ g, float* __restrict__ outp,
                  const u16* __restrict__ wq0_hi, const u16* __restrict__ wq0_lo,
                  const u16* __restrict__ wc_hi,  const u16* __restrict__ wc_lo,
                  const u16* __restrict__ wo1_hi, const u16* __restrict__ wo1_lo,
                  const float* __restrict__ bq,   const float* __restrict__ bout1) {
  extern __shared__ char lds[];
  const int tid  = threadIdx.x;
  const int lane = tid & 63;
  const int wave = tid >> 6;
  const int b    = blockIdx.y;
  const int pos0 = blockIdx.x * PTILE;

  // ---- stage z tile (32 rows x 256) into A_hi/A_lo frags @0/16K ----
  {
    const int r   = tid >> 4;          // 0..31
    const int cb  = (tid & 15) * 16;
    const int pos = pos0 + (r >> 2);
    const int tok = r & 3;
    const float* src;
    if (tok == 0)      src = x + ((size_t)b * NP + pos) * DIM;
    else if (tok == 1) src = y + ((size_t)b * NP + pos) * DIM;
    else if (tok == 2) src = g + b * DIM;
    else               src = g + (8 + b) * DIM;
    const int sw = (r & 15) << 4;
#pragma unroll
    for (int u = 0; u < 4; u++) {
      const int col = cb + u * 4;
      float4 v = *(const float4*)(src + col);
      uint2 hw, lw;
      hw.x = cvt_pk(v.x, v.y);
      hw.y = cvt_pk(v.z, v.w);
      const float lx = v.x - bflo(hw.x), ly = v.y - bfhi(hw.x);
      const float lz = v.z - bflo(hw.y), lww = v.w - bfhi(hw.y);
      lw.x = cvt_pk(lx, ly);
      lw.y = cvt_pk(lz, lww);
      const int bo = (r * 512 + col * 2) ^ sw;
      *(uint2*)(lds + bo)         = hw;
      *(uint2*)(lds + 16384 + bo) = lw;
    }
  }
  __syncthreads();
  phase_fence();

  // ---- stage 0 (A@0) -> attnout0 frags @32K/48K ----
  stage_attn<0, false>(lds, 0, tid, lane, wave, wq0_hi, wq0_lo, nullptr);

  // ---- stage 1 (A = attnout0 @32K, W_combo + bq) -> attnout1 @0/16K ----
  stage_attn<1, true>(lds, 32768, tid, lane, wave, wc_hi, wc_lo, bq);

  // ---- GEMM2: out(32x256) = attnout1 @0/16K . Wout1^T ----
  const int arow = lane & 31;
  const int kgrp = (lane >> 5) << 3;
  f32x16 acc2;
#pragma unroll
  for (int i = 0; i < 16; i++) acc2[i] = 0.f;

#pragma unroll 4
  for (int ks = 0; ks < 16; ks++) {
    const int bo = (arow * 512 + (ks * 16 + kgrp) * 2) ^ ((arow & 15) << 4);
    bf16x8 ahi = *(const bf16x8*)(lds + bo);
    bf16x8 alo = *(const bf16x8*)(lds + 16384 + bo);
    const size_t o = (((size_t)wave * 16 + ks) * 64 + lane) * 8;
    bf16x8 bhi = *(const bf16x8*)(wo1_hi + o);
    bf16x8 blo = *(const bf16x8*)(wo1_lo + o);
    __builtin_amdgcn_s_setprio(1);
    acc2 = __builtin_amdgcn_mfma_f32_32x32x16_bf16(ahi, bhi, acc2, 0, 0, 0);
    acc2 = __builtin_amdgcn_mfma_f32_32x32x16_bf16(ahi, blo, acc2, 0, 0, 0);
    acc2 = __builtin_amdgcn_mfma_f32_32x32x16_bf16(alo, bhi, acc2, 0, 0, 0);
    __builtin_amdgcn_s_setprio(0);
  }

  // ---- epilogue: tok0 -> x1, tok1 -> y1 ----
  {
    const int c  = wave * 32 + (lane & 31);
    const int rh = (lane >> 5) << 2;
    const float bc = bout1[c];
    const size_t TOT = (size_t)NB * NP * DIM;
#pragma unroll
    for (int i = 0; i < 16; i++) {
      const int r   = (i & 3) + ((i >> 2) << 3) + rh;
      const int pos = pos0 + (r >> 2);
      const int tok = r & 3;
      const float v = acc2[i] + bc;
      if (tok == 0)      outp[((size_t)b * NP + pos) * DIM + c] = v;
      else if (tok == 1) outp[TOT + ((size_t)b * NP + pos) * DIM + c] = v;
    }
  }
}

extern "C" void kernel_launch(void* const* d_in, const int* in_sizes, int n_in,
                              void* d_out, int out_size, void* d_ws, size_t ws_size,
                              hipStream_t stream) {
  const float* x     = (const float*)d_in[0];
  const float* y     = (const float*)d_in[1];
  const float* wqkv0 = (const float*)d_in[2];
  const float* wout0 = (const float*)d_in[3];
  const float* bout0 = (const float*)d_in[4];
  const float* wqkv1 = (const float*)d_in[5];
  const float* wout1 = (const float*)d_in[6];
  const float* bout1 = (const float*)d_in[7];

  float* part = (float*)d_ws;                        // 16*32*256 f32
  float* g    = part + (size_t)16 * 32 * DIM;        // 16*256 f32
  float* Wc   = g + 16 * DIM;                        // 768*256 f32
  float* bq   = Wc + 768 * 256;                      // 768 f32
  u16* w = (u16*)(bq + 768);
  u16* wq0_hi = w; w += 768 * 256;
  u16* wq0_lo = w; w += 768 * 256;
  u16* wc_hi  = w; w += 768 * 256;
  u16* wc_lo  = w; w += 768 * 256;
  u16* wo1_hi = w; w += 256 * 256;
  u16* wo1_lo = w; w += 256 * 256;

  mean_partial<<<dim3(32, 16), dim3(256), 0, stream>>>(x, y, part);
  mean_final<<<dim3(16), dim3(256), 0, stream>>>(part, g);

  combo_w<<<dim3(96), dim3(256), 0, stream>>>(wqkv1, wout0, Wc);
  combo_b<<<dim3(3), dim3(256), 0, stream>>>(wqkv1, bout0, bq);

  pack_w<<<dim3(24, 16), dim3(64), 0, stream>>>(wqkv0, wq0_hi, wq0_lo, 1);
  pack_w<<<dim3(24, 16), dim3(64), 0, stream>>>(Wc,    wc_hi,  wc_lo,  1);
  pack_w<<<dim3(8, 16),  dim3(64), 0, stream>>>(wout1, wo1_hi, wo1_lo, 0);

  fused_kernel<<<dim3(NP / PTILE, NB), dim3(512), LDS_SZ, stream>>>(
      x, y, g, (float*)d_out,
      wq0_hi, wq0_lo, wc_hi, wc_lo, wo1_hi, wo1_lo, bq, bout1);
}

// Round 9
// 361.870 us; speedup vs baseline: 1.7824x; 1.1273x over previous
//
#include <hip/hip_runtime.h>

typedef unsigned short u16;
typedef unsigned int   u32;
typedef short bf16x8 __attribute__((ext_vector_type(8)));
typedef float f32x16 __attribute__((ext_vector_type(16)));

#define NB    8
#define NP    3136
#define DIM   256
#define PTILE 8
#define NEGM  (-100.0f)
#define QKSCALE 0.17677669529663687f

// LDS (64 KiB), ping-pong between two 32K halves:
// stage0: A-frags @0/16K; Q/K col-major @32K/48K; V f32 @0..32K (A dead);
//         attnout frags @32K/48K (QK dead).
// stage1: A = attnout0 @32K/48K; Q/K @0/16K; V @32K..64K; attnout1 @0/16K.
#define LDS_SZ  65536

__device__ __forceinline__ float bflo(u32 w) { return __uint_as_float(w << 16); }
__device__ __forceinline__ float bfhi(u32 w) { return __uint_as_float(w & 0xffff0000u); }

// packed f32x2 -> bf16x2 (RTNE), 1 VALU op
__device__ __forceinline__ u32 cvt_pk(float a, float b) {
  u32 r;
  asm("v_cvt_pk_bf16_f32 %0, %1, %2" : "=v"(r) : "v"(a), "v"(b));
  return r;
}

__device__ __forceinline__ void phase_fence() {
  __builtin_amdgcn_sched_barrier(0);
}

template<int MASKI>
__device__ __forceinline__ float maskv(int i, int j) {
  if (MASKI == 0) return ((i ^ j) == 3) ? NEGM : 0.f;
  return (i >= 2 || ((i ^ j) & 1)) ? NEGM : 0.f;
}

// ---------------- shared pack helper: 4 (nt,ks) fragment pairs / block -----
__device__ __forceinline__ void pack4(const float* __restrict__ W,
                                      u16* __restrict__ hi, u16* __restrict__ lo,
                                      int is_qkv, int pair0, int tid) {
  const int p    = pair0 + (tid >> 6);
  const int lane = tid & 63;
  const int nt = p >> 4, ks = p & 15;
  const int n  = nt * 32 + (lane & 31);
  const int k0 = ks * 16 + ((lane >> 5) << 3);
  const float scale = (is_qkv && n < 256) ? QKSCALE : 1.0f;
  const float* src = W + (size_t)n * 256 + k0;
  const size_t o = (((size_t)nt * 16 + ks) * 64 + lane) * 8;
#pragma unroll
  for (int j = 0; j < 8; j++) {
    float v = src[j] * scale;
    u32 wh = cvt_pk(v, v);
    float l = v - bflo(wh);
    u32 wl = cvt_pk(l, l);
    hi[o + j] = (u16)wh;
    lo[o + j] = (u16)wl;
  }
}

// ---------------- prologue mega-kernel 1 ----------------
// blocks [0,512): mean partials; [512,608): pack wqkv0; [608,640): pack wout1;
// [640,1408): combo_w rows; [1408,1411): combo_b.
__global__ __launch_bounds__(256)
void prep1(const float* __restrict__ x, const float* __restrict__ y,
           float* __restrict__ part,
           const float* __restrict__ wqkv0, u16* __restrict__ wq0_hi, u16* __restrict__ wq0_lo,
           const float* __restrict__ wout1, u16* __restrict__ wo1_hi, u16* __restrict__ wo1_lo,
           const float* __restrict__ wqkv1, const float* __restrict__ wout0,
           float* __restrict__ Wc,
           const float* __restrict__ bout0, float* __restrict__ bq) {
  __shared__ float srow[256];
  const int bid = blockIdx.x;
  const int tid = threadIdx.x;
  if (bid < 512) {                       // mean_partial
    const int chunk = bid & 31;
    const int ab = bid >> 5;
    const int b = ab & 7;
    const float* src = (ab >> 3) ? y : x;
    float s = 0.f;
    const int p0 = chunk * 98;  // 3136 = 32*98
    for (int i = 0; i < 98; i++)
      s += src[((size_t)b * NP + p0 + i) * DIM + tid];
    part[((size_t)ab * 32 + chunk) * DIM + tid] = s;
  } else if (bid < 608) {                // pack wqkv0 (384 pairs)
    pack4(wqkv0, wq0_hi, wq0_lo, 1, (bid - 512) * 4, tid);
  } else if (bid < 640) {                // pack wout1 (128 pairs)
    pack4(wout1, wo1_hi, wo1_lo, 0, (bid - 608) * 4, tid);
  } else if (bid < 1408) {               // combo_w: Wc[n][e] = sum_d Wq1[n][d]*Wo0[d][e]
    const int n = bid - 640;
    srow[tid] = wqkv1[(size_t)n * 256 + tid];
    __syncthreads();
    float acc = 0.f;
#pragma unroll 8
    for (int d = 0; d < 256; d++)
      acc += srow[d] * wout0[(size_t)d * 256 + tid];
    Wc[(size_t)n * 256 + tid] = acc;
  } else {                               // combo_b: bq = Wq1 . bout0 (Q rows scaled)
    const int n = (bid - 1408) * 256 + tid;
    float s = 0.f;
    for (int d = 0; d < 256; d += 4) {
      const float4 w = *(const float4*)(wqkv1 + (size_t)n * 256 + d);
      const float4 b = *(const float4*)(bout0 + d);
      s += w.x * b.x + w.y * b.y + w.z * b.z + w.w * b.w;
    }
    bq[n] = (n < 256) ? s * QKSCALE : s;
  }
}

// ---------------- prologue mega-kernel 2 ----------------
// blocks [0,16): mean_final; [16,112): pack Wc (384 pairs).
__global__ __launch_bounds__(256)
void prep2(const float* __restrict__ part, float* __restrict__ g,
           const float* __restrict__ Wc, u16* __restrict__ wc_hi, u16* __restrict__ wc_lo) {
  const int bid = blockIdx.x;
  const int tid = threadIdx.x;
  if (bid < 16) {
    float s = 0.f;
    for (int c = 0; c < 32; c++) s += part[((size_t)bid * 32 + c) * DIM + tid];
    g[bid * DIM + tid] = s * (1.0f / 3136.0f);
  } else {
    pack4(Wc, wc_hi, wc_lo, 1, (bid - 16) * 4, tid);
  }
}

// ---------------- per-stage GEMM1 + attention ----------------
// Entry: A-frags (hi@ABASE, lo@ABASE+16K) staged, barrier passed.
// Exit: attnout hi/lo A-frags @QKB / QKB+16K, where QKB = ABASE ^ 32768.
template<int MASKI, bool QB>
__device__ __forceinline__ void stage_attn(
    char* lds, const int ABASE, int tid, int lane, int wave,
    const u16* __restrict__ w_hi, const u16* __restrict__ w_lo,
    const float* __restrict__ qbias) {

  const int QKB  = ABASE ^ 32768;
  const int arow = lane & 31;
  const int kgrp = (lane >> 5) << 3;
  const int cl   = lane & 31;
  const int rh5  = lane >> 5;        // 0/1

  // ---- GEMM1 ks-outer: wave w computes {w}=Q, {8+w}=K, {16+w}=V (head=w).
  // A-frag pair read ONCE per ks, feeds all 3 tiles (3x fewer LDS reads).
  f32x16 acc0, acc1, accV;
#pragma unroll
  for (int i = 0; i < 16; i++) { acc0[i] = 0.f; acc1[i] = 0.f; accV[i] = 0.f; }
#pragma unroll 2
  for (int ks = 0; ks < 16; ks++) {
    const int bo = ABASE + ((arow * 512 + (ks * 16 + kgrp) * 2) ^ ((arow & 15) << 4));
    bf16x8 ahi = *(const bf16x8*)(lds + bo);
    bf16x8 alo = *(const bf16x8*)(lds + 16384 + bo);
    const size_t o0 = (((size_t)wave * 16 + ks) * 64 + lane) * 8;
    const size_t o1 = (((size_t)(8 + wave) * 16 + ks) * 64 + lane) * 8;
    const size_t o2 = (((size_t)(16 + wave) * 16 + ks) * 64 + lane) * 8;
    bf16x8 b0h = *(const bf16x8*)(w_hi + o0);
    bf16x8 b0l = *(const bf16x8*)(w_lo + o0);
    bf16x8 b1h = *(const bf16x8*)(w_hi + o1);
    bf16x8 b1l = *(const bf16x8*)(w_lo + o1);
    bf16x8 b2h = *(const bf16x8*)(w_hi + o2);
    bf16x8 b2l = *(const bf16x8*)(w_lo + o2);
    __builtin_amdgcn_s_setprio(1);
    acc0 = __builtin_amdgcn_mfma_f32_32x32x16_bf16(ahi, b0h, acc0, 0, 0, 0);
    acc0 = __builtin_amdgcn_mfma_f32_32x32x16_bf16(ahi, b0l, acc0, 0, 0, 0);
    acc0 = __builtin_amdgcn_mfma_f32_32x32x16_bf16(alo, b0h, acc0, 0, 0, 0);
    acc1 = __builtin_amdgcn_mfma_f32_32x32x16_bf16(ahi, b1h, acc1, 0, 0, 0);
    acc1 = __builtin_amdgcn_mfma_f32_32x32x16_bf16(ahi, b1l, acc1, 0, 0, 0);
    acc1 = __builtin_amdgcn_mfma_f32_32x32x16_bf16(alo, b1h, acc1, 0, 0, 0);
    accV = __builtin_amdgcn_mfma_f32_32x32x16_bf16(ahi, b2h, accV, 0, 0, 0);
    accV = __builtin_amdgcn_mfma_f32_32x32x16_bf16(ahi, b2l, accV, 0, 0, 0);
    accV = __builtin_amdgcn_mfma_f32_32x32x16_bf16(alo, b2h, accV, 0, 0, 0);
    __builtin_amdgcn_s_setprio(0);
  }
  if (QB) {
    const float qb0 = qbias[wave * 32 + cl];
    const float qb1 = qbias[256 + wave * 32 + cl];
    const float qbV = qbias[512 + wave * 32 + cl];
#pragma unroll
    for (int i = 0; i < 16; i++) { acc0[i] += qb0; acc1[i] += qb1; accV[i] += qbV; }
  }
  // ---- scatter Q (acc0) / K (acc1) col-major [h=wave][d=cl][tok], b64 packs
  {
    const int sw = ((cl >> 2) & 7) << 3;
    const int baseQ = QKB + wave * 2048 + cl * 64;
#pragma unroll
    for (int g = 0; g < 4; g++) {
      uint2 wv;
      wv.x = cvt_pk(acc0[4 * g + 0], acc0[4 * g + 1]);
      wv.y = cvt_pk(acc0[4 * g + 2], acc0[4 * g + 3]);
      *(uint2*)(lds + baseQ + (((rh5 + 2 * g) * 8) ^ sw)) = wv;
    }
    const int baseK = QKB + 16384 + wave * 2048 + cl * 64;
#pragma unroll
    for (int g = 0; g < 4; g++) {
      uint2 wv;
      wv.x = cvt_pk(acc1[4 * g + 0], acc1[4 * g + 1]);
      wv.y = cvt_pk(acc1[4 * g + 2], acc1[4 * g + 3]);
      *(uint2*)(lds + baseK + (((rh5 + 2 * g) * 8) ^ sw)) = wv;
    }
  }
  __syncthreads();  // all waves done reading A region
  phase_fence();

  // ---- V scatter (f32 col-major @ABASE, XOR ((d>>2)&7)<<4) ∥ dots ----
  {
    const int vbase = ABASE + wave * 4096 + cl * 128;
    const int swv = ((cl >> 2) & 7) << 4;
#pragma unroll
    for (int p = 0; p < 8; p++) {
      const int i = 2 * p;
      const int r = (i & 3) + ((i >> 2) << 3) + rh5 * 4;  // even tok
      float2 vv;
      vv.x = accV[i];
      vv.y = accV[i + 1];
      *(float2*)(lds + vbase + ((r * 4) ^ swv)) = vv;
    }
  }

  // ---- attention dots: wave = pos-group, head = lane>>3, dgrp = lane&7 ----
  const int dgrp  = lane & 7;
  const int ahead = lane >> 3;
  float p[4][4];
  {
    uint2 qw[4], kw[4];
    const int qoff = ahead * 2048 + dgrp * 256 + ((wave * 8) ^ (dgrp << 3));
#pragma unroll
    for (int dd = 0; dd < 4; dd++) {
      qw[dd] = *(const uint2*)(lds + QKB + qoff + dd * 64);
      kw[dd] = *(const uint2*)(lds + QKB + 16384 + qoff + dd * 64);
    }
    float dots[4][4];
#pragma unroll
    for (int i = 0; i < 4; i++)
#pragma unroll
      for (int j = 0; j < 4; j++) dots[i][j] = 0.f;
#pragma unroll
    for (int dd = 0; dd < 4; dd++) {
      const float q0 = bflo(qw[dd].x), q1 = bfhi(qw[dd].x);
      const float q2 = bflo(qw[dd].y), q3 = bfhi(qw[dd].y);
      const float k0 = bflo(kw[dd].x), k1 = bfhi(kw[dd].x);
      const float k2 = bflo(kw[dd].y), k3 = bfhi(kw[dd].y);
      dots[0][0] += q0 * k0; dots[0][1] += q0 * k1; dots[0][2] += q0 * k2; dots[0][3] += q0 * k3;
      dots[1][0] += q1 * k0; dots[1][1] += q1 * k1; dots[1][2] += q1 * k2; dots[1][3] += q1 * k3;
      dots[2][0] += q2 * k0; dots[2][1] += q2 * k1; dots[2][2] += q2 * k2; dots[2][3] += q2 * k3;
      dots[3][0] += q3 * k0; dots[3][1] += q3 * k1; dots[3][2] += q3 * k2; dots[3][3] += q3 * k3;
    }
#pragma unroll
    for (int i = 0; i < 4; i++)
#pragma unroll
      for (int j = 0; j < 4; j++) {
        float s = dots[i][j];
        s += __shfl_xor(s, 1);
        s += __shfl_xor(s, 2);
        s += __shfl_xor(s, 4);
        dots[i][j] = s;
      }
#pragma unroll
    for (int i = 0; i < 4; i++) {
      const float d0 = dots[i][0] + maskv<MASKI>(i, 0);
      const float d1 = dots[i][1] + maskv<MASKI>(i, 1);
      const float d2 = dots[i][2] + maskv<MASKI>(i, 2);
      const float d3 = dots[i][3] + maskv<MASKI>(i, 3);
      const float mx = fmaxf(fmaxf(d0, d1), fmaxf(d2, d3));
      const float e0 = __expf(d0 - mx), e1 = __expf(d1 - mx);
      const float e2 = __expf(d2 - mx), e3 = __expf(d3 - mx);
      const float inv = 1.f / (e0 + e1 + e2 + e3);
      p[i][0] = e0 * inv; p[i][1] = e1 * inv;
      p[i][2] = e2 * inv; p[i][3] = e3 * inv;
    }
  }
  __syncthreads();  // V writes visible; all Q/K reads done
  phase_fence();

  // ---- PV (4 dims/thread) + attnout hi/lo A-frags @QKB / QKB+16K ----
  {
    const int voff = ABASE + ahead * 4096 + dgrp * 512 + ((wave * 16) ^ (dgrp << 4));
    const float4 v0 = *(const float4*)(lds + voff + 0);
    const float4 v1 = *(const float4*)(lds + voff + 128);
    const float4 v2 = *(const float4*)(lds + voff + 256);
    const float4 v3 = *(const float4*)(lds + voff + 384);
#pragma unroll
    for (int ti = 0; ti < 4; ti++) {
      const float o0 = p[ti][0] * v0.x + p[ti][1] * v0.y + p[ti][2] * v0.z + p[ti][3] * v0.w;
      const float o1 = p[ti][0] * v1.x + p[ti][1] * v1.y + p[ti][2] * v1.z + p[ti][3] * v1.w;
      const float o2 = p[ti][0] * v2.x + p[ti][1] * v2.y + p[ti][2] * v2.z + p[ti][3] * v2.w;
      const float o3 = p[ti][0] * v3.x + p[ti][1] * v3.y + p[ti][2] * v3.z + p[ti][3] * v3.w;
      const int R = wave * 4 + ti;
      const u32 h0 = cvt_pk(o0, o1), h1 = cvt_pk(o2, o3);
      const float l0 = o0 - bflo(h0), l1 = o1 - bfhi(h0);
      const float l2 = o2 - bflo(h1), l3 = o3 - bfhi(h1);
      const u32 g0 = cvt_pk(l0, l1), g1 = cvt_pk(l2, l3);
      const int bo = QKB + ((R * 512 + ahead * 64 + dgrp * 8) ^ ((R & 15) << 4));
      uint2 hw; hw.x = h0; hw.y = h1;
      uint2 lw; lw.x = g0; lw.y = g1;
      *(uint2*)(lds + bo)         = hw;
      *(uint2*)(lds + 16384 + bo) = lw;
    }
  }
  __syncthreads();  // attnout ready as next A
  phase_fence();
}

// ---------------- fused double-stage kernel ----------------
__global__ __launch_bounds__(512, 4)
void fused_kernel(const float* __restrict__ x, const float* __restrict__ y,
                  const float* __restrict__ g, float* __restrict__ outp,
                  const u16* __restrict__ wq0_hi, const u16* __restrict__ wq0_lo,
                  const u16* __restrict__ wc_hi,  const u16* __restrict__ wc_lo,
                  const u16* __restrict__ wo1_hi, const u16* __restrict__ wo1_lo,
                  const float* __restrict__ bq,   const float* __restrict__ bout1) {
  extern __shared__ char lds[];
  const int tid  = threadIdx.x;
  const int lane = tid & 63;
  const int wave = tid >> 6;
  const int b    = blockIdx.y;
  const int pos0 = blockIdx.x * PTILE;

  // ---- stage z tile (32 rows x 256) into A_hi/A_lo frags @0/16K ----
  {
    const int r   = tid >> 4;          // 0..31
    const int cb  = (tid & 15) * 16;
    const int pos = pos0 + (r >> 2);
    const int tok = r & 3;
    const float* src;
    if (tok == 0)      src = x + ((size_t)b * NP + pos) * DIM;
    else if (tok == 1) src = y + ((size_t)b * NP + pos) * DIM;
    else if (tok == 2) src = g + b * DIM;
    else               src = g + (8 + b) * DIM;
    const int sw = (r & 15) << 4;
#pragma unroll
    for (int u = 0; u < 4; u++) {
      const int col = cb + u * 4;
      float4 v = *(const float4*)(src + col);
      uint2 hw, lw;
      hw.x = cvt_pk(v.x, v.y);
      hw.y = cvt_pk(v.z, v.w);
      const float lx = v.x - bflo(hw.x), ly = v.y - bfhi(hw.x);
      const float lz = v.z - bflo(hw.y), lww = v.w - bfhi(hw.y);
      lw.x = cvt_pk(lx, ly);
      lw.y = cvt_pk(lz, lww);
      const int bo = (r * 512 + col * 2) ^ sw;
      *(uint2*)(lds + bo)         = hw;
      *(uint2*)(lds + 16384 + bo) = lw;
    }
  }
  __syncthreads();
  phase_fence();

  // ---- stage 0 (A@0) -> attnout0 frags @32K/48K ----
  stage_attn<0, false>(lds, 0, tid, lane, wave, wq0_hi, wq0_lo, nullptr);

  // ---- stage 1 (A = attnout0 @32K, W_combo + bq) -> attnout1 @0/16K ----
  stage_attn<1, true>(lds, 32768, tid, lane, wave, wc_hi, wc_lo, bq);

  // ---- GEMM2: out(32x256) = attnout1 @0/16K . Wout1^T ----
  const int arow = lane & 31;
  const int kgrp = (lane >> 5) << 3;
  f32x16 acc2;
#pragma unroll
  for (int i = 0; i < 16; i++) acc2[i] = 0.f;

#pragma unroll 4
  for (int ks = 0; ks < 16; ks++) {
    const int bo = (arow * 512 + (ks * 16 + kgrp) * 2) ^ ((arow & 15) << 4);
    bf16x8 ahi = *(const bf16x8*)(lds + bo);
    bf16x8 alo = *(const bf16x8*)(lds + 16384 + bo);
    const size_t o = (((size_t)wave * 16 + ks) * 64 + lane) * 8;
    bf16x8 bhi = *(const bf16x8*)(wo1_hi + o);
    bf16x8 blo = *(const bf16x8*)(wo1_lo + o);
    __builtin_amdgcn_s_setprio(1);
    acc2 = __builtin_amdgcn_mfma_f32_32x32x16_bf16(ahi, bhi, acc2, 0, 0, 0);
    acc2 = __builtin_amdgcn_mfma_f32_32x32x16_bf16(ahi, blo, acc2, 0, 0, 0);
    acc2 = __builtin_amdgcn_mfma_f32_32x32x16_bf16(alo, bhi, acc2, 0, 0, 0);
    __builtin_amdgcn_s_setprio(0);
  }

  // ---- epilogue: tok0 -> x1, tok1 -> y1 ----
  {
    const int c  = wave * 32 + (lane & 31);
    const int rh = (lane >> 5) << 2;
    const float bc = bout1[c];
    const size_t TOT = (size_t)NB * NP * DIM;
#pragma unroll
    for (int i = 0; i < 16; i++) {
      const int r   = (i & 3) + ((i >> 2) << 3) + rh;
      const int pos = pos0 + (r >> 2);
      const int tok = r & 3;
      const float v = acc2[i] + bc;
      if (tok == 0)      outp[((size_t)b * NP + pos) * DIM + c] = v;
      else if (tok == 1) outp[TOT + ((size_t)b * NP + pos) * DIM + c] = v;
    }
  }
}

extern "C" void kernel_launch(void* const* d_in, const int* in_sizes, int n_in,
                              void* d_out, int out_size, void* d_ws, size_t ws_size,
                              hipStream_t stream) {
  const float* x     = (const float*)d_in[0];
  const float* y     = (const float*)d_in[1];
  const float* wqkv0 = (const float*)d_in[2];
  const float* wout0 = (const float*)d_in[3];
  const float* bout0 = (const float*)d_in[4];
  const float* wqkv1 = (const float*)d_in[5];
  const float* wout1 = (const float*)d_in[6];
  const float* bout1 = (const float*)d_in[7];

  float* part = (float*)d_ws;                        // 16*32*256 f32
  float* g    = part + (size_t)16 * 32 * DIM;        // 16*256 f32
  float* Wc   = g + 16 * DIM;                        // 768*256 f32
  float* bq   = Wc + 768 * 256;                      // 768 f32
  u16* w = (u16*)(bq + 768);
  u16* wq0_hi = w; w += 768 * 256;
  u16* wq0_lo = w; w += 768 * 256;
  u16* wc_hi  = w; w += 768 * 256;
  u16* wc_lo  = w; w += 768 * 256;
  u16* wo1_hi = w; w += 256 * 256;
  u16* wo1_lo = w; w += 256 * 256;

  prep1<<<dim3(1411), dim3(256), 0, stream>>>(
      x, y, part, wqkv0, wq0_hi, wq0_lo, wout1, wo1_hi, wo1_lo,
      wqkv1, wout0, Wc, bout0, bq);
  prep2<<<dim3(112), dim3(256), 0, stream>>>(part, g, Wc, wc_hi, wc_lo);

  fused_kernel<<<dim3(NP / PTILE, NB), dim3(512), LDS_SZ, stream>>>(
      x, y, g, (float*)d_out,
      wq0_hi, wq0_lo, wc_hi, wc_lo, wo1_hi, wo1_lo, bq, bout1);
}